// Round 1
// baseline (698.930 us; speedup 1.0000x reference)
//
#include <hip/hip_runtime.h>
#include <hip/hip_bf16.h>
#include <math.h>

#define N_TOK 2048
#define H_DIM 1024
#define N_EXP 16
#define I_DIM 768
#define TOPK 4
#define SCALE 2.5f

typedef __attribute__((ext_vector_type(8))) short bf16x8;
typedef __attribute__((ext_vector_type(4))) float f32x4;

// workspace layout (bytes)
#define OFF_COUNTS   0
#define OFF_OFFSETS  128
#define OFF_TOKIDS   256
#define OFF_TOKW     (256 + N_EXP*N_TOK*4)
#define OFF_XB       (OFF_TOKW + N_EXP*N_TOK*4)
#define OFF_HACT     (OFF_XB + N_TOK*H_DIM*2)
// hact: (N_TOK*TOPK + N_TOK) slots * I_DIM * 2B = 15.7 MB; total ~20.2 MB

__device__ __forceinline__ ushort f2bf(float f) {
    union { __hip_bfloat16 h; ushort u; } cv;
    cv.h = __float2bfloat16(f);
    return cv.u;
}
__device__ __forceinline__ unsigned pack2(float lo, float hi) {
    return (unsigned)f2bf(lo) | ((unsigned)f2bf(hi) << 16);
}

// ---------------- x -> bf16 ----------------
__global__ void k_convert(const float* __restrict__ x, ushort* __restrict__ xb) {
    int idx = (blockIdx.x * 256 + threadIdx.x) * 4;
    float4 v = *(const float4*)(x + idx);
    uint2 p;
    p.x = pack2(v.x, v.y);
    p.y = pack2(v.z, v.w);
    *(uint2*)(xb + idx) = p;
}

// ---------------- routing ----------------
__global__ void k_route(const float* __restrict__ x, const float* __restrict__ gw,
                        const float* __restrict__ gb,
                        int* __restrict__ counts, int* __restrict__ tok_ids,
                        float* __restrict__ tok_w) {
    int n = blockIdx.x;
    int lane = threadIdx.x;  // 64 threads
    __shared__ float logits[N_EXP];
    float xr[16];
    const float* xrow = x + (size_t)n * H_DIM;
#pragma unroll
    for (int j = 0; j < 16; j++) xr[j] = xrow[lane + 64 * j];
    for (int e = 0; e < N_EXP; e++) {
        const float* g = gw + e * H_DIM;
        float p = 0.f;
#pragma unroll
        for (int j = 0; j < 16; j++) p += xr[j] * g[lane + 64 * j];
#pragma unroll
        for (int off = 32; off > 0; off >>= 1) p += __shfl_down(p, off);
        if (lane == 0) logits[e] = p;
    }
    __syncthreads();
    if (lane == 0) {
        float sc[N_EXP], sb[N_EXP];
        for (int e = 0; e < N_EXP; e++) {
            sc[e] = 1.f / (1.f + expf(-logits[e]));
            sb[e] = sc[e] + gb[e];
        }
        // group scores = sum of top-2 biased scores per group of 4
        float gsc[4];
        for (int g = 0; g < 4; g++) {
            float m1 = -1e30f, m2 = -1e30f;
            for (int j = 0; j < 4; j++) {
                float v = sb[4 * g + j];
                if (v > m1) { m2 = m1; m1 = v; }
                else if (v > m2) m2 = v;
            }
            gsc[g] = m1 + m2;
        }
        int g1 = 0;
        for (int g = 1; g < 4; g++) if (gsc[g] > gsc[g1]) g1 = g;
        int g2 = -1;
        for (int g = 0; g < 4; g++) {
            if (g == g1) continue;
            if (g2 < 0 || gsc[g] > gsc[g2]) g2 = g;
        }
        bool allowed[N_EXP];
        for (int e = 0; e < N_EXP; e++) {
            int grp = e >> 2;
            allowed[e] = (grp == g1) || (grp == g2);
        }
        int chosen[TOPK];
        float wsum = 0.f;
        for (int k = 0; k < TOPK; k++) {
            int best = -1;
            for (int e = 0; e < N_EXP; e++) {
                if (!allowed[e]) continue;
                if (best < 0 || sb[e] > sb[best]) best = e;
            }
            chosen[k] = best;
            allowed[best] = false;
            wsum += sc[best];
        }
        float inv = SCALE / (wsum + 1e-20f);
        for (int k = 0; k < TOPK; k++) {
            int e = chosen[k];
            int p = atomicAdd(&counts[e], 1);
            tok_ids[e * N_TOK + p] = n;
            tok_w[e * N_TOK + p] = sc[e] * inv;
        }
    }
}

// ---------------- offsets scan ----------------
__global__ void k_scan(const int* __restrict__ counts, int* __restrict__ offsets) {
    if (threadIdx.x == 0 && blockIdx.x == 0) {
        int off = 0;
        for (int e = 0; e < N_EXP; e++) { offsets[e] = off; off += counts[e]; }
        offsets[N_EXP] = off;  // shared expert base (= 8192)
    }
}

// ---------------- stage A: gate/up proj + silu, gathered ----------------
__launch_bounds__(256)
__global__ void k_gateup(const ushort* __restrict__ xb, const float* __restrict__ w1,
                         const float* __restrict__ w3, const float* __restrict__ ws1,
                         const float* __restrict__ ws3, const int* __restrict__ counts,
                         const int* __restrict__ offsets, const int* __restrict__ tok_ids,
                         const float* __restrict__ tok_w, ushort* __restrict__ hact) {
    int e = blockIdx.z;
    int m0 = blockIdx.x * 64;
    int i0 = blockIdx.y * 64;
    int Me = (e == N_EXP) ? N_TOK : counts[e];
    if (m0 >= Me) return;
    const float* W1 = (e == N_EXP) ? ws1 : w1 + (size_t)e * I_DIM * H_DIM;
    const float* W3 = (e == N_EXP) ? ws3 : w3 + (size_t)e * I_DIM * H_DIM;
    const int* list = tok_ids + e * N_TOK;
    const float* wl = tok_w + e * N_TOK;
    int base = offsets[e];

    __shared__ ushort As[64][72];
    __shared__ ushort B1s[64][72];
    __shared__ ushort B3s[64][72];
    __shared__ float tws[64];

    int tid = threadIdx.x;
    if (tid < 64) {
        int r = m0 + tid;
        if (e == N_EXP) tws[tid] = 1.f;
        else tws[tid] = (r < Me) ? wl[r] : 0.f;
    }
    int r = tid >> 2, c0 = (tid & 3) * 16;
    int tok;
    if (e == N_EXP) tok = m0 + r;
    else tok = (m0 + r < Me) ? list[m0 + r] : -1;

    int wv = tid >> 6, lane = tid & 63;
    int quad = lane >> 4, lr = lane & 15;
    int wm = (wv & 1) * 32, wn = (wv >> 1) * 32;
    f32x4 accg[2][2] = {};
    f32x4 accu[2][2] = {};

    for (int k0 = 0; k0 < H_DIM; k0 += 64) {
        // stage A (bf16 gathered rows)
        uint4 z; z.x = z.y = z.z = z.w = 0u;
        uint4 v0 = z, v1 = z;
        if (tok >= 0) {
            const uint4* src = (const uint4*)(xb + (size_t)tok * H_DIM + k0 + c0);
            v0 = src[0]; v1 = src[1];
        }
        *(uint4*)&As[r][c0] = v0;
        *(uint4*)&As[r][c0 + 8] = v1;
        // stage B1/B3 (fp32 -> bf16)
        {
            const float* b1 = W1 + (size_t)(i0 + r) * H_DIM + k0 + c0;
            float4 f0 = *(const float4*)(b1);
            float4 f1 = *(const float4*)(b1 + 4);
            float4 f2 = *(const float4*)(b1 + 8);
            float4 f3 = *(const float4*)(b1 + 12);
            uint4 p0, p1;
            p0.x = pack2(f0.x, f0.y); p0.y = pack2(f0.z, f0.w);
            p0.z = pack2(f1.x, f1.y); p0.w = pack2(f1.z, f1.w);
            p1.x = pack2(f2.x, f2.y); p1.y = pack2(f2.z, f2.w);
            p1.z = pack2(f3.x, f3.y); p1.w = pack2(f3.z, f3.w);
            *(uint4*)&B1s[r][c0] = p0;
            *(uint4*)&B1s[r][c0 + 8] = p1;
        }
        {
            const float* b3 = W3 + (size_t)(i0 + r) * H_DIM + k0 + c0;
            float4 f0 = *(const float4*)(b3);
            float4 f1 = *(const float4*)(b3 + 4);
            float4 f2 = *(const float4*)(b3 + 8);
            float4 f3 = *(const float4*)(b3 + 12);
            uint4 p0, p1;
            p0.x = pack2(f0.x, f0.y); p0.y = pack2(f0.z, f0.w);
            p0.z = pack2(f1.x, f1.y); p0.w = pack2(f1.z, f1.w);
            p1.x = pack2(f2.x, f2.y); p1.y = pack2(f2.z, f2.w);
            p1.z = pack2(f3.x, f3.y); p1.w = pack2(f3.z, f3.w);
            *(uint4*)&B3s[r][c0] = p0;
            *(uint4*)&B3s[r][c0 + 8] = p1;
        }
        __syncthreads();
#pragma unroll
        for (int ks = 0; ks < 2; ks++) {
            int kb = ks * 32 + quad * 8;
            bf16x8 a0 = *(const bf16x8*)&As[wm + lr][kb];
            bf16x8 a1 = *(const bf16x8*)&As[wm + 16 + lr][kb];
            bf16x8 b10 = *(const bf16x8*)&B1s[wn + lr][kb];
            bf16x8 b11 = *(const bf16x8*)&B1s[wn + 16 + lr][kb];
            bf16x8 b30 = *(const bf16x8*)&B3s[wn + lr][kb];
            bf16x8 b31 = *(const bf16x8*)&B3s[wn + 16 + lr][kb];
            accg[0][0] = __builtin_amdgcn_mfma_f32_16x16x32_bf16(a0, b10, accg[0][0], 0, 0, 0);
            accg[0][1] = __builtin_amdgcn_mfma_f32_16x16x32_bf16(a0, b11, accg[0][1], 0, 0, 0);
            accg[1][0] = __builtin_amdgcn_mfma_f32_16x16x32_bf16(a1, b10, accg[1][0], 0, 0, 0);
            accg[1][1] = __builtin_amdgcn_mfma_f32_16x16x32_bf16(a1, b11, accg[1][1], 0, 0, 0);
            accu[0][0] = __builtin_amdgcn_mfma_f32_16x16x32_bf16(a0, b30, accu[0][0], 0, 0, 0);
            accu[0][1] = __builtin_amdgcn_mfma_f32_16x16x32_bf16(a0, b31, accu[0][1], 0, 0, 0);
            accu[1][0] = __builtin_amdgcn_mfma_f32_16x16x32_bf16(a1, b30, accu[1][0], 0, 0, 0);
            accu[1][1] = __builtin_amdgcn_mfma_f32_16x16x32_bf16(a1, b31, accu[1][1], 0, 0, 0);
        }
        __syncthreads();
    }
    // epilogue: silu(g)*u*tw -> hact (bf16)
#pragma unroll
    for (int mi = 0; mi < 2; mi++) {
#pragma unroll
        for (int ni = 0; ni < 2; ni++) {
            f32x4 g = accg[mi][ni];
            f32x4 u = accu[mi][ni];
#pragma unroll
            for (int rg = 0; rg < 4; rg++) {
                int ml = wm + mi * 16 + quad * 4 + rg;
                int row = m0 + ml;
                if (row < Me) {
                    float gg = g[rg], uu = u[rg];
                    float act = (gg / (1.f + expf(-gg))) * uu * tws[ml];
                    hact[(size_t)(base + row) * I_DIM + i0 + wn + ni * 16 + lr] = f2bf(act);
                }
            }
        }
    }
}

// ---------------- stage B: down proj + scatter-add ----------------
__launch_bounds__(256)
__global__ void k_down(const ushort* __restrict__ hact, const float* __restrict__ w2,
                       const float* __restrict__ ws2, const int* __restrict__ counts,
                       const int* __restrict__ offsets, const int* __restrict__ tok_ids,
                       float* __restrict__ out) {
    int e = blockIdx.z;
    int m0 = blockIdx.x * 64;
    int h0 = blockIdx.y * 64;
    int Me = (e == N_EXP) ? N_TOK : counts[e];
    if (m0 >= Me) return;
    const float* W2 = (e == N_EXP) ? ws2 : w2 + (size_t)e * H_DIM * I_DIM;
    int base = offsets[e];

    __shared__ ushort As[64][72];
    __shared__ ushort Bs[64][72];
    __shared__ int toks[64];

    int tid = threadIdx.x;
    if (tid < 64) {
        int r = m0 + tid;
        toks[tid] = (e == N_EXP) ? r : ((r < Me) ? tok_ids[e * N_TOK + r] : 0);
    }
    int r = tid >> 2, c0 = (tid & 3) * 16;
    bool arow_ok = (m0 + r) < Me;
    const ushort* asrc = hact + (size_t)(base + m0 + r) * I_DIM;

    int wv = tid >> 6, lane = tid & 63;
    int quad = lane >> 4, lr = lane & 15;
    int wm = (wv & 1) * 32, wn = (wv >> 1) * 32;
    f32x4 acc[2][2] = {};

    for (int k0 = 0; k0 < I_DIM; k0 += 64) {
        uint4 z; z.x = z.y = z.z = z.w = 0u;
        uint4 v0 = z, v1 = z;
        if (arow_ok) {
            const uint4* s = (const uint4*)(asrc + k0 + c0);
            v0 = s[0]; v1 = s[1];
        }
        *(uint4*)&As[r][c0] = v0;
        *(uint4*)&As[r][c0 + 8] = v1;
        {
            const float* b = W2 + (size_t)(h0 + r) * I_DIM + k0 + c0;
            float4 f0 = *(const float4*)(b);
            float4 f1 = *(const float4*)(b + 4);
            float4 f2 = *(const float4*)(b + 8);
            float4 f3 = *(const float4*)(b + 12);
            uint4 p0, p1;
            p0.x = pack2(f0.x, f0.y); p0.y = pack2(f0.z, f0.w);
            p0.z = pack2(f1.x, f1.y); p0.w = pack2(f1.z, f1.w);
            p1.x = pack2(f2.x, f2.y); p1.y = pack2(f2.z, f2.w);
            p1.z = pack2(f3.x, f3.y); p1.w = pack2(f3.z, f3.w);
            *(uint4*)&Bs[r][c0] = p0;
            *(uint4*)&Bs[r][c0 + 8] = p1;
        }
        __syncthreads();
#pragma unroll
        for (int ks = 0; ks < 2; ks++) {
            int kb = ks * 32 + quad * 8;
            bf16x8 a0 = *(const bf16x8*)&As[wm + lr][kb];
            bf16x8 a1 = *(const bf16x8*)&As[wm + 16 + lr][kb];
            bf16x8 b0 = *(const bf16x8*)&Bs[wn + lr][kb];
            bf16x8 b1 = *(const bf16x8*)&Bs[wn + 16 + lr][kb];
            acc[0][0] = __builtin_amdgcn_mfma_f32_16x16x32_bf16(a0, b0, acc[0][0], 0, 0, 0);
            acc[0][1] = __builtin_amdgcn_mfma_f32_16x16x32_bf16(a0, b1, acc[0][1], 0, 0, 0);
            acc[1][0] = __builtin_amdgcn_mfma_f32_16x16x32_bf16(a1, b0, acc[1][0], 0, 0, 0);
            acc[1][1] = __builtin_amdgcn_mfma_f32_16x16x32_bf16(a1, b1, acc[1][1], 0, 0, 0);
        }
        __syncthreads();
    }
#pragma unroll
    for (int mi = 0; mi < 2; mi++) {
#pragma unroll
        for (int ni = 0; ni < 2; ni++) {
#pragma unroll
            for (int rg = 0; rg < 4; rg++) {
                int ml = wm + mi * 16 + quad * 4 + rg;
                int row = m0 + ml;
                if (row < Me) {
                    int tok = toks[ml];
                    atomicAdd(&out[(size_t)tok * H_DIM + h0 + wn + ni * 16 + lr],
                              acc[mi][ni][rg]);
                }
            }
        }
    }
}

extern "C" void kernel_launch(void* const* d_in, const int* in_sizes, int n_in,
                              void* d_out, int out_size, void* d_ws, size_t ws_size,
                              hipStream_t stream) {
    const float* x   = (const float*)d_in[0];
    const float* gw  = (const float*)d_in[1];
    const float* gb  = (const float*)d_in[2];
    const float* w1  = (const float*)d_in[3];
    const float* w2  = (const float*)d_in[4];
    const float* w3  = (const float*)d_in[5];
    const float* ws1 = (const float*)d_in[6];
    const float* ws2 = (const float*)d_in[7];
    const float* ws3 = (const float*)d_in[8];
    float* out = (float*)d_out;

    char* wsb = (char*)d_ws;
    int* counts   = (int*)(wsb + OFF_COUNTS);
    int* offsets  = (int*)(wsb + OFF_OFFSETS);
    int* tok_ids  = (int*)(wsb + OFF_TOKIDS);
    float* tok_w  = (float*)(wsb + OFF_TOKW);
    ushort* xb    = (ushort*)(wsb + OFF_XB);
    ushort* hact  = (ushort*)(wsb + OFF_HACT);

    hipMemsetAsync(wsb, 0, 256, stream);                       // counts
    hipMemsetAsync(d_out, 0, (size_t)out_size * 4, stream);    // zero outputs

    k_convert<<<N_TOK * H_DIM / (256 * 4), 256, 0, stream>>>(x, xb);
    k_route<<<N_TOK, 64, 0, stream>>>(x, gw, gb, counts, tok_ids, tok_w);
    k_scan<<<1, 1, 0, stream>>>(counts, offsets);
    {
        dim3 grid(N_TOK / 64, I_DIM / 64, N_EXP + 1);
        k_gateup<<<grid, 256, 0, stream>>>(xb, w1, w3, ws1, ws3, counts, offsets,
                                           tok_ids, tok_w, hact);
    }
    {
        dim3 grid(N_TOK / 64, H_DIM / 64, N_EXP + 1);
        k_down<<<grid, 256, 0, stream>>>(hact, w2, ws2, counts, offsets, tok_ids, out);
    }
}

// Round 2
// 643.083 us; speedup vs baseline: 1.0868x; 1.0868x over previous
//
#include <hip/hip_runtime.h>
#include <hip/hip_bf16.h>
#include <math.h>

#define N_TOK 2048
#define H_DIM 1024
#define N_EXP 16
#define I_DIM 768
#define TOPK 4
#define SCALE 2.5f

typedef __attribute__((ext_vector_type(8))) short bf16x8;
typedef __attribute__((ext_vector_type(4))) float f32x4;

// workspace layout (bytes)
#define OFF_COUNTS   0
#define OFF_OFFSETS  128
#define OFF_TOKIDS   256
#define OFF_TOKW     (256 + N_EXP*N_TOK*4)
#define OFF_XB       (OFF_TOKW + N_EXP*N_TOK*4)
#define OFF_HACT     (OFF_XB + N_TOK*H_DIM*2)
// hact: (N_TOK*TOPK + N_TOK) slots * I_DIM * 2B = 15.7 MB; total ~20.2 MB

__device__ __forceinline__ ushort f2bf(float f) {
    union { __hip_bfloat16 h; ushort u; } cv;
    cv.h = __float2bfloat16(f);
    return cv.u;
}
__device__ __forceinline__ unsigned pack2(float lo, float hi) {
    return (unsigned)f2bf(lo) | ((unsigned)f2bf(hi) << 16);
}
__device__ __forceinline__ void async_copy16(const void* g, void* l) {
    __builtin_amdgcn_global_load_lds(
        (const __attribute__((address_space(1))) unsigned int*)g,
        (__attribute__((address_space(3))) unsigned int*)l, 16, 0, 0);
}
__device__ __forceinline__ uint4 pack16(const float* p) {
    float4 f0 = *(const float4*)(p);
    float4 f1 = *(const float4*)(p + 4);
    uint4 o;
    o.x = pack2(f0.x, f0.y); o.y = pack2(f0.z, f0.w);
    o.z = pack2(f1.x, f1.y); o.w = pack2(f1.z, f1.w);
    return o;
}

// ---------------- x -> bf16 ----------------
__global__ void k_convert(const float* __restrict__ x, ushort* __restrict__ xb) {
    int idx = (blockIdx.x * 256 + threadIdx.x) * 4;
    float4 v = *(const float4*)(x + idx);
    uint2 p;
    p.x = pack2(v.x, v.y);
    p.y = pack2(v.z, v.w);
    *(uint2*)(xb + idx) = p;
}

// ---------------- routing ----------------
__global__ void k_route(const float* __restrict__ x, const float* __restrict__ gw,
                        const float* __restrict__ gb,
                        int* __restrict__ counts, int* __restrict__ tok_ids,
                        float* __restrict__ tok_w) {
    int n = blockIdx.x;
    int lane = threadIdx.x;  // 64 threads
    __shared__ float logits[N_EXP];
    float xr[16];
    const float* xrow = x + (size_t)n * H_DIM;
#pragma unroll
    for (int j = 0; j < 16; j++) xr[j] = xrow[lane + 64 * j];
    for (int e = 0; e < N_EXP; e++) {
        const float* g = gw + e * H_DIM;
        float p = 0.f;
#pragma unroll
        for (int j = 0; j < 16; j++) p += xr[j] * g[lane + 64 * j];
#pragma unroll
        for (int off = 32; off > 0; off >>= 1) p += __shfl_down(p, off);
        if (lane == 0) logits[e] = p;
    }
    __syncthreads();
    if (lane == 0) {
        float sc[N_EXP], sb[N_EXP];
        for (int e = 0; e < N_EXP; e++) {
            sc[e] = 1.f / (1.f + expf(-logits[e]));
            sb[e] = sc[e] + gb[e];
        }
        float gsc[4];
        for (int g = 0; g < 4; g++) {
            float m1 = -1e30f, m2 = -1e30f;
            for (int j = 0; j < 4; j++) {
                float v = sb[4 * g + j];
                if (v > m1) { m2 = m1; m1 = v; }
                else if (v > m2) m2 = v;
            }
            gsc[g] = m1 + m2;
        }
        int g1 = 0;
        for (int g = 1; g < 4; g++) if (gsc[g] > gsc[g1]) g1 = g;
        int g2 = -1;
        for (int g = 0; g < 4; g++) {
            if (g == g1) continue;
            if (g2 < 0 || gsc[g] > gsc[g2]) g2 = g;
        }
        bool allowed[N_EXP];
        for (int e = 0; e < N_EXP; e++) {
            int grp = e >> 2;
            allowed[e] = (grp == g1) || (grp == g2);
        }
        int chosen[TOPK];
        float wsum = 0.f;
        for (int k = 0; k < TOPK; k++) {
            int best = -1;
            for (int e = 0; e < N_EXP; e++) {
                if (!allowed[e]) continue;
                if (best < 0 || sb[e] > sb[best]) best = e;
            }
            chosen[k] = best;
            allowed[best] = false;
            wsum += sc[best];
        }
        float inv = SCALE / (wsum + 1e-20f);
        for (int k = 0; k < TOPK; k++) {
            int e = chosen[k];
            int p = atomicAdd(&counts[e], 1);
            tok_ids[e * N_TOK + p] = n;
            tok_w[e * N_TOK + p] = sc[e] * inv;
        }
    }
}

// ---------------- offsets scan ----------------
__global__ void k_scan(const int* __restrict__ counts, int* __restrict__ offsets) {
    if (threadIdx.x == 0 && blockIdx.x == 0) {
        int off = 0;
        for (int e = 0; e < N_EXP; e++) { offsets[e] = off; off += counts[e]; }
        offsets[N_EXP] = off;  // shared expert base (= 8192)
    }
}

// ---------------- stage A: gate/up proj + silu, gathered ----------------
// tile: M=128 tokens, N=64 intermediate, K-block=64 over H=1024
__launch_bounds__(256)
__global__ void k_gateup(const ushort* __restrict__ xb, const float* __restrict__ w1,
                         const float* __restrict__ w3, const float* __restrict__ ws1,
                         const float* __restrict__ ws3, const int* __restrict__ counts,
                         const int* __restrict__ offsets, const int* __restrict__ tok_ids,
                         const float* __restrict__ tok_w, ushort* __restrict__ hact) {
    int e = blockIdx.z;
    int m0 = blockIdx.x * 128;
    int i0 = blockIdx.y * 64;
    int Me = (e == N_EXP) ? N_TOK : counts[e];
    if (m0 >= Me) return;
    const float* W1 = (e == N_EXP) ? ws1 : w1 + (size_t)e * I_DIM * H_DIM;
    const float* W3 = (e == N_EXP) ? ws3 : w3 + (size_t)e * I_DIM * H_DIM;
    int base = offsets[e];

    __shared__ ushort As[128][64];   // unpadded: required by global_load_lds layout
    __shared__ ushort B1s[64][72];
    __shared__ ushort B3s[64][72];
    __shared__ float tws[128];

    int tid = threadIdx.x;
    int wv = tid >> 6, lane = tid & 63;

    if (tid < 128) {
        int r = m0 + tid;
        float w = 1.f;
        if (e != N_EXP) w = (r < Me) ? tok_w[e * N_TOK + r] : 0.f;
        tws[tid] = w;
    }

    // A-load setup: wave wv, issue j covers rows wv*32 + j*8 .. +8
    // lane -> row offset lane>>3, 16B segment lane&7
    const ushort* abase[4];
    int seg = lane & 7;
#pragma unroll
    for (int j = 0; j < 4; j++) {
        int row = wv * 32 + j * 8 + (lane >> 3);
        int gr = m0 + row;
        int tok;
        if (e == N_EXP) tok = gr;
        else tok = (gr < Me) ? tok_ids[e * N_TOK + gr] : 0;
        abase[j] = xb + (size_t)tok * H_DIM + seg * 8;
    }
    // B-load setup: thread -> row tid>>2, 16-col chunk (tid&3)*16
    int brow = tid >> 2, bc = (tid & 3) * 16;
    const float* b1p = W1 + (size_t)(i0 + brow) * H_DIM + bc;
    const float* b3p = W3 + (size_t)(i0 + brow) * H_DIM + bc;

    int quad = lane >> 4, lr = lane & 15;
    f32x4 accg[2][4] = {};
    f32x4 accu[2][4] = {};

    for (int k0 = 0; k0 < H_DIM; k0 += 64) {
#pragma unroll
        for (int j = 0; j < 4; j++)
            async_copy16(abase[j] + k0, &As[wv * 32 + j * 8][0]);
        uint4 p1a = pack16(b1p + k0);
        uint4 p1b = pack16(b1p + k0 + 8);
        uint4 p3a = pack16(b3p + k0);
        uint4 p3b = pack16(b3p + k0 + 8);
        *(uint4*)&B1s[brow][bc] = p1a;
        *(uint4*)&B1s[brow][bc + 8] = p1b;
        *(uint4*)&B3s[brow][bc] = p3a;
        *(uint4*)&B3s[brow][bc + 8] = p3b;
        __syncthreads();
#pragma unroll
        for (int ks = 0; ks < 2; ks++) {
            int kb = ks * 32 + quad * 8;
            bf16x8 a0 = *(const bf16x8*)&As[wv * 32 + lr][kb];
            bf16x8 a1 = *(const bf16x8*)&As[wv * 32 + 16 + lr][kb];
#pragma unroll
            for (int ni = 0; ni < 4; ni++) {
                bf16x8 bf1 = *(const bf16x8*)&B1s[ni * 16 + lr][kb];
                bf16x8 bf3 = *(const bf16x8*)&B3s[ni * 16 + lr][kb];
                accg[0][ni] = __builtin_amdgcn_mfma_f32_16x16x32_bf16(a0, bf1, accg[0][ni], 0, 0, 0);
                accg[1][ni] = __builtin_amdgcn_mfma_f32_16x16x32_bf16(a1, bf1, accg[1][ni], 0, 0, 0);
                accu[0][ni] = __builtin_amdgcn_mfma_f32_16x16x32_bf16(a0, bf3, accu[0][ni], 0, 0, 0);
                accu[1][ni] = __builtin_amdgcn_mfma_f32_16x16x32_bf16(a1, bf3, accu[1][ni], 0, 0, 0);
            }
        }
        __syncthreads();
    }
    // epilogue: silu(g)*u*tw -> hact bf16
#pragma unroll
    for (int mi = 0; mi < 2; mi++) {
#pragma unroll
        for (int ni = 0; ni < 4; ni++) {
            f32x4 g = accg[mi][ni];
            f32x4 u = accu[mi][ni];
#pragma unroll
            for (int rg = 0; rg < 4; rg++) {
                int ml = wv * 32 + mi * 16 + quad * 4 + rg;
                int row = m0 + ml;
                if (row < Me) {
                    float gg = g[rg], uu = u[rg];
                    float act = (gg / (1.f + expf(-gg))) * uu * tws[ml];
                    hact[(size_t)(base + row) * I_DIM + i0 + ni * 16 + lr] = f2bf(act);
                }
            }
        }
    }
}

// ---------------- stage B: down proj + scatter-add ----------------
// tile: M=128 slots, N=64 of H, K-block=64 over I=768
__launch_bounds__(256)
__global__ void k_down(const ushort* __restrict__ hact, const float* __restrict__ w2,
                       const float* __restrict__ ws2, const int* __restrict__ counts,
                       const int* __restrict__ offsets, const int* __restrict__ tok_ids,
                       float* __restrict__ out) {
    int e = blockIdx.z;
    int m0 = blockIdx.x * 128;
    int h0 = blockIdx.y * 64;
    int Me = (e == N_EXP) ? N_TOK : counts[e];
    if (m0 >= Me) return;
    const float* W2 = (e == N_EXP) ? ws2 : w2 + (size_t)e * H_DIM * I_DIM;
    int base = offsets[e];

    __shared__ ushort As[128][64];
    __shared__ ushort Bs[64][72];
    __shared__ int toks[128];

    int tid = threadIdx.x;
    int wv = tid >> 6, lane = tid & 63;

    if (tid < 128) {
        int r = m0 + tid;
        toks[tid] = (e == N_EXP) ? r : ((r < Me) ? tok_ids[e * N_TOK + r] : 0);
    }
    // A rows are contiguous slots
    int seg = lane & 7;
    const ushort* abase[4];
#pragma unroll
    for (int j = 0; j < 4; j++) {
        int row = wv * 32 + j * 8 + (lane >> 3);
        abase[j] = hact + (size_t)(base + m0 + row) * I_DIM + seg * 8;
    }
    int brow = tid >> 2, bc = (tid & 3) * 16;
    const float* bp = W2 + (size_t)(h0 + brow) * I_DIM + bc;

    int quad = lane >> 4, lr = lane & 15;
    f32x4 acc[2][4] = {};

    for (int k0 = 0; k0 < I_DIM; k0 += 64) {
#pragma unroll
        for (int j = 0; j < 4; j++)
            async_copy16(abase[j] + k0, &As[wv * 32 + j * 8][0]);
        uint4 pa = pack16(bp + k0);
        uint4 pb = pack16(bp + k0 + 8);
        *(uint4*)&Bs[brow][bc] = pa;
        *(uint4*)&Bs[brow][bc + 8] = pb;
        __syncthreads();
#pragma unroll
        for (int ks = 0; ks < 2; ks++) {
            int kb = ks * 32 + quad * 8;
            bf16x8 a0 = *(const bf16x8*)&As[wv * 32 + lr][kb];
            bf16x8 a1 = *(const bf16x8*)&As[wv * 32 + 16 + lr][kb];
#pragma unroll
            for (int ni = 0; ni < 4; ni++) {
                bf16x8 bf = *(const bf16x8*)&Bs[ni * 16 + lr][kb];
                acc[0][ni] = __builtin_amdgcn_mfma_f32_16x16x32_bf16(a0, bf, acc[0][ni], 0, 0, 0);
                acc[1][ni] = __builtin_amdgcn_mfma_f32_16x16x32_bf16(a1, bf, acc[1][ni], 0, 0, 0);
            }
        }
        __syncthreads();
    }
#pragma unroll
    for (int mi = 0; mi < 2; mi++) {
#pragma unroll
        for (int ni = 0; ni < 4; ni++) {
#pragma unroll
            for (int rg = 0; rg < 4; rg++) {
                int ml = wv * 32 + mi * 16 + quad * 4 + rg;
                int row = m0 + ml;
                if (row < Me) {
                    int tok = toks[ml];
                    atomicAdd(&out[(size_t)tok * H_DIM + h0 + ni * 16 + lr],
                              acc[mi][ni][rg]);
                }
            }
        }
    }
}

extern "C" void kernel_launch(void* const* d_in, const int* in_sizes, int n_in,
                              void* d_out, int out_size, void* d_ws, size_t ws_size,
                              hipStream_t stream) {
    const float* x   = (const float*)d_in[0];
    const float* gw  = (const float*)d_in[1];
    const float* gb  = (const float*)d_in[2];
    const float* w1  = (const float*)d_in[3];
    const float* w2  = (const float*)d_in[4];
    const float* w3  = (const float*)d_in[5];
    const float* ws1 = (const float*)d_in[6];
    const float* ws2 = (const float*)d_in[7];
    const float* ws3 = (const float*)d_in[8];
    float* out = (float*)d_out;

    char* wsb = (char*)d_ws;
    int* counts   = (int*)(wsb + OFF_COUNTS);
    int* offsets  = (int*)(wsb + OFF_OFFSETS);
    int* tok_ids  = (int*)(wsb + OFF_TOKIDS);
    float* tok_w  = (float*)(wsb + OFF_TOKW);
    ushort* xb    = (ushort*)(wsb + OFF_XB);
    ushort* hact  = (ushort*)(wsb + OFF_HACT);

    hipMemsetAsync(wsb, 0, 256, stream);                       // counts
    hipMemsetAsync(d_out, 0, (size_t)out_size * 4, stream);    // zero outputs

    k_convert<<<N_TOK * H_DIM / (256 * 4), 256, 0, stream>>>(x, xb);
    k_route<<<N_TOK, 64, 0, stream>>>(x, gw, gb, counts, tok_ids, tok_w);
    k_scan<<<1, 1, 0, stream>>>(counts, offsets);
    {
        dim3 grid(N_TOK / 128, I_DIM / 64, N_EXP + 1);
        k_gateup<<<grid, 256, 0, stream>>>(xb, w1, w3, ws1, ws3, counts, offsets,
                                           tok_ids, tok_w, hact);
    }
    {
        dim3 grid(N_TOK / 128, H_DIM / 64, N_EXP + 1);
        k_down<<<grid, 256, 0, stream>>>(hact, w2, ws2, counts, offsets, tok_ids, out);
    }
}

// Round 3
// 550.626 us; speedup vs baseline: 1.2693x; 1.1679x over previous
//
#include <hip/hip_runtime.h>
#include <hip/hip_bf16.h>
#include <math.h>

#define N_TOK 2048
#define H_DIM 1024
#define N_EXP 16
#define I_DIM 768
#define TOPK 4
#define SCALE 2.5f

typedef __attribute__((ext_vector_type(8))) short bf16x8;
typedef __attribute__((ext_vector_type(4))) float f32x4;

// s_waitcnt simm16 (gfx9): vmcnt[3:0] | expcnt[6:4] | lgkmcnt[11:8]
#define WAIT_VM(n) ((n) | (7 << 4) | (15 << 8))

// workspace layout (bytes)
#define OFF_COUNTS   0
#define OFF_OFFSETS  128
#define OFF_TOKIDS   256
#define OFF_TOKW     (OFF_TOKIDS + N_EXP*N_TOK*4)
#define OFF_XB       (OFF_TOKW + N_EXP*N_TOK*4)
#define OFF_HACT     (OFF_XB + (size_t)N_TOK*H_DIM*2)
#define OFF_WB1      (OFF_HACT + (size_t)N_TOK*(TOPK+1)*I_DIM*2)
#define OFF_WB2      (OFF_WB1 + (size_t)N_EXP*I_DIM*H_DIM*2)
#define OFF_WB3      (OFF_WB2 + (size_t)N_EXP*H_DIM*I_DIM*2)
#define OFF_WSB1     (OFF_WB3 + (size_t)N_EXP*I_DIM*H_DIM*2)
#define OFF_WSB2     (OFF_WSB1 + (size_t)I_DIM*H_DIM*2)
#define OFF_WSB3     (OFF_WSB2 + (size_t)H_DIM*I_DIM*2)
// total ~100.4 MB

__device__ __forceinline__ ushort f2bf(float f) {
    union { __hip_bfloat16 h; ushort u; } cv;
    cv.h = __float2bfloat16(f);
    return cv.u;
}
__device__ __forceinline__ unsigned pack2(float lo, float hi) {
    return (unsigned)f2bf(lo) | ((unsigned)f2bf(hi) << 16);
}
__device__ __forceinline__ void async_copy16(const void* g, void* l) {
    __builtin_amdgcn_global_load_lds(
        (const __attribute__((address_space(1))) unsigned int*)g,
        (__attribute__((address_space(3))) unsigned int*)l, 16, 0, 0);
}

// ---------------- fp32 -> bf16 bulk convert (weights + x) ----------------
struct WcArgs {
    const float* src[7];
    ushort* dst[7];
    int n4[7];
};
__global__ void k_wconv(WcArgs a) {
    int id = blockIdx.y;
    const float4* s = (const float4*)a.src[id];
    uint2* d = (uint2*)a.dst[id];
    int n4 = a.n4[id];
    int stride = gridDim.x * 256;
    for (int i = blockIdx.x * 256 + threadIdx.x; i < n4; i += stride) {
        float4 v = s[i];
        uint2 p;
        p.x = pack2(v.x, v.y);
        p.y = pack2(v.z, v.w);
        d[i] = p;
    }
}

// ---------------- routing ----------------
__global__ void k_route(const float* __restrict__ x, const float* __restrict__ gw,
                        const float* __restrict__ gb,
                        int* __restrict__ counts, int* __restrict__ tok_ids,
                        float* __restrict__ tok_w) {
    int n = blockIdx.x;
    int lane = threadIdx.x;  // 64 threads
    __shared__ float logits[N_EXP];
    float xr[16];
    const float* xrow = x + (size_t)n * H_DIM;
#pragma unroll
    for (int j = 0; j < 16; j++) xr[j] = xrow[lane + 64 * j];
    for (int e = 0; e < N_EXP; e++) {
        const float* g = gw + e * H_DIM;
        float p = 0.f;
#pragma unroll
        for (int j = 0; j < 16; j++) p += xr[j] * g[lane + 64 * j];
#pragma unroll
        for (int off = 32; off > 0; off >>= 1) p += __shfl_down(p, off);
        if (lane == 0) logits[e] = p;
    }
    __syncthreads();
    if (lane == 0) {
        float sc[N_EXP], sb[N_EXP];
        for (int e = 0; e < N_EXP; e++) {
            sc[e] = 1.f / (1.f + expf(-logits[e]));
            sb[e] = sc[e] + gb[e];
        }
        float gsc[4];
        for (int g = 0; g < 4; g++) {
            float m1 = -1e30f, m2 = -1e30f;
            for (int j = 0; j < 4; j++) {
                float v = sb[4 * g + j];
                if (v > m1) { m2 = m1; m1 = v; }
                else if (v > m2) m2 = v;
            }
            gsc[g] = m1 + m2;
        }
        int g1 = 0;
        for (int g = 1; g < 4; g++) if (gsc[g] > gsc[g1]) g1 = g;
        int g2 = -1;
        for (int g = 0; g < 4; g++) {
            if (g == g1) continue;
            if (g2 < 0 || gsc[g] > gsc[g2]) g2 = g;
        }
        bool allowed[N_EXP];
        for (int e = 0; e < N_EXP; e++) {
            int grp = e >> 2;
            allowed[e] = (grp == g1) || (grp == g2);
        }
        int chosen[TOPK];
        float wsum = 0.f;
        for (int k = 0; k < TOPK; k++) {
            int best = -1;
            for (int e = 0; e < N_EXP; e++) {
                if (!allowed[e]) continue;
                if (best < 0 || sb[e] > sb[best]) best = e;
            }
            chosen[k] = best;
            allowed[best] = false;
            wsum += sc[best];
        }
        float inv = SCALE / (wsum + 1e-20f);
        for (int k = 0; k < TOPK; k++) {
            int e = chosen[k];
            int p = atomicAdd(&counts[e], 1);
            tok_ids[e * N_TOK + p] = n;
            tok_w[e * N_TOK + p] = sc[e] * inv;
        }
    }
}

// ---------------- offsets scan ----------------
__global__ void k_scan(const int* __restrict__ counts, int* __restrict__ offsets) {
    if (threadIdx.x == 0 && blockIdx.x == 0) {
        int off = 0;
        for (int e = 0; e < N_EXP; e++) { offsets[e] = off; off += counts[e]; }
        offsets[N_EXP] = off;  // shared expert base (= 8192)
    }
}

// ---------------- stage A: gate/up proj + silu, gathered ----------------
// M=128, N=64 (both w1,w3), BK=64; double-buffered async LDS, XOR-swizzled.
__launch_bounds__(256)
__global__ void k_gateup(const ushort* __restrict__ xb, const ushort* __restrict__ wb1,
                         const ushort* __restrict__ wb3, const ushort* __restrict__ wsb1,
                         const ushort* __restrict__ wsb3, const int* __restrict__ counts,
                         const int* __restrict__ offsets, const int* __restrict__ tok_ids,
                         const float* __restrict__ tok_w, ushort* __restrict__ hact) {
    int e = blockIdx.z;
    int m0 = blockIdx.x * 128;
    int i0 = blockIdx.y * 64;
    int Me = (e == N_EXP) ? N_TOK : counts[e];
    if (m0 >= Me) return;
    const ushort* W1 = (e == N_EXP) ? wsb1 : wb1 + (size_t)e * I_DIM * H_DIM;
    const ushort* W3 = (e == N_EXP) ? wsb3 : wb3 + (size_t)e * I_DIM * H_DIM;
    int base = offsets[e];

    __shared__ ushort As[2][128][64];
    __shared__ ushort B1s[2][64][64];
    __shared__ ushort B3s[2][64][64];
    __shared__ float tws[128];

    int tid = threadIdx.x;
    int wv = tid >> 6, lane = tid & 63;
    int seg = lane & 7, rsub = lane >> 3;
    int gch = (seg ^ rsub) * 8;   // swizzled source chunk (element offset)

    if (tid < 128) {
        int r = m0 + tid;
        tws[tid] = (e == N_EXP) ? 1.f : ((r < Me) ? tok_w[e * N_TOK + r] : 0.f);
    }

    // per-lane source pointers (swizzle applied on the global side)
    const ushort* aptr[4];
#pragma unroll
    for (int j = 0; j < 4; j++) {
        int gr = m0 + wv * 32 + j * 8 + rsub;
        int tok = (e == N_EXP) ? gr : ((gr < Me) ? tok_ids[e * N_TOK + gr] : 0);
        aptr[j] = xb + (size_t)tok * H_DIM + gch;
    }
    const ushort *b1ptr[2], *b3ptr[2];
#pragma unroll
    for (int j = 0; j < 2; j++) {
        int row = i0 + wv * 16 + j * 8 + rsub;
        b1ptr[j] = W1 + (size_t)row * H_DIM + gch;
        b3ptr[j] = W3 + (size_t)row * H_DIM + gch;
    }

    int quad = lane >> 4, lr = lane & 15, rx = lr & 7;
    f32x4 accg[2][4] = {};
    f32x4 accu[2][4] = {};

    // prologue: fill buffer 0
#pragma unroll
    for (int j = 0; j < 4; j++) async_copy16(aptr[j], &As[0][wv * 32 + j * 8][0]);
#pragma unroll
    for (int j = 0; j < 2; j++) async_copy16(b1ptr[j], &B1s[0][wv * 16 + j * 8][0]);
#pragma unroll
    for (int j = 0; j < 2; j++) async_copy16(b3ptr[j], &B3s[0][wv * 16 + j * 8][0]);
    __syncthreads();  // buf0 ready + tws visible

    const int NK = H_DIM / 64;
    for (int k = 0; k < NK; k++) {
        int buf = k & 1;
        if (k + 1 < NK) {
            int off = (k + 1) * 64;
#pragma unroll
            for (int j = 0; j < 4; j++) async_copy16(aptr[j] + off, &As[1 - buf][wv * 32 + j * 8][0]);
#pragma unroll
            for (int j = 0; j < 2; j++) async_copy16(b1ptr[j] + off, &B1s[1 - buf][wv * 16 + j * 8][0]);
#pragma unroll
            for (int j = 0; j < 2; j++) async_copy16(b3ptr[j] + off, &B3s[1 - buf][wv * 16 + j * 8][0]);
            __builtin_amdgcn_s_waitcnt(WAIT_VM(8));  // wait cur buf only; prefetch in flight
        } else {
            __builtin_amdgcn_s_waitcnt(WAIT_VM(0));
        }
        __builtin_amdgcn_s_barrier();
#pragma unroll
        for (int ks = 0; ks < 2; ks++) {
            int co = ((ks * 4 + quad) ^ rx) * 8;  // swizzled read chunk
            bf16x8 a0 = *(const bf16x8*)&As[buf][wv * 32 + lr][co];
            bf16x8 a1 = *(const bf16x8*)&As[buf][wv * 32 + 16 + lr][co];
#pragma unroll
            for (int ni = 0; ni < 4; ni++) {
                bf16x8 bf1 = *(const bf16x8*)&B1s[buf][ni * 16 + lr][co];
                bf16x8 bf3 = *(const bf16x8*)&B3s[buf][ni * 16 + lr][co];
                accg[0][ni] = __builtin_amdgcn_mfma_f32_16x16x32_bf16(a0, bf1, accg[0][ni], 0, 0, 0);
                accg[1][ni] = __builtin_amdgcn_mfma_f32_16x16x32_bf16(a1, bf1, accg[1][ni], 0, 0, 0);
                accu[0][ni] = __builtin_amdgcn_mfma_f32_16x16x32_bf16(a0, bf3, accu[0][ni], 0, 0, 0);
                accu[1][ni] = __builtin_amdgcn_mfma_f32_16x16x32_bf16(a1, bf3, accu[1][ni], 0, 0, 0);
            }
        }
        __builtin_amdgcn_s_barrier();  // all waves done reading buf before it is refilled
    }

    // epilogue: silu(g)*u*tw -> hact bf16
#pragma unroll
    for (int mi = 0; mi < 2; mi++) {
#pragma unroll
        for (int ni = 0; ni < 4; ni++) {
            f32x4 g = accg[mi][ni];
            f32x4 u = accu[mi][ni];
#pragma unroll
            for (int rg = 0; rg < 4; rg++) {
                int ml = wv * 32 + mi * 16 + quad * 4 + rg;
                int row = m0 + ml;
                if (row < Me) {
                    float gg = g[rg], uu = u[rg];
                    float act = (gg / (1.f + expf(-gg))) * uu * tws[ml];
                    hact[(size_t)(base + row) * I_DIM + i0 + ni * 16 + lr] = f2bf(act);
                }
            }
        }
    }
}

// ---------------- stage B: down proj + scatter-add ----------------
// M=128 slots, N=64 of H, BK=64 over I=768; same pipeline.
__launch_bounds__(256)
__global__ void k_down(const ushort* __restrict__ hact, const ushort* __restrict__ wb2,
                       const ushort* __restrict__ wsb2, const int* __restrict__ counts,
                       const int* __restrict__ offsets, const int* __restrict__ tok_ids,
                       float* __restrict__ out) {
    int e = blockIdx.z;
    int m0 = blockIdx.x * 128;
    int h0 = blockIdx.y * 64;
    int Me = (e == N_EXP) ? N_TOK : counts[e];
    if (m0 >= Me) return;
    const ushort* W2 = (e == N_EXP) ? wsb2 : wb2 + (size_t)e * H_DIM * I_DIM;
    int base = offsets[e];

    __shared__ ushort As[2][128][64];
    __shared__ ushort Bs[2][64][64];
    __shared__ int toks[128];

    int tid = threadIdx.x;
    int wv = tid >> 6, lane = tid & 63;
    int seg = lane & 7, rsub = lane >> 3;
    int gch = (seg ^ rsub) * 8;

    if (tid < 128) {
        int r = m0 + tid;
        toks[tid] = (e == N_EXP) ? r : ((r < Me) ? tok_ids[e * N_TOK + r] : 0);
    }

    const ushort* aptr[4];
#pragma unroll
    for (int j = 0; j < 4; j++) {
        int row = wv * 32 + j * 8 + rsub;
        aptr[j] = hact + (size_t)(base + m0 + row) * I_DIM + gch;
    }
    const ushort* bptr[2];
#pragma unroll
    for (int j = 0; j < 2; j++) {
        int row = h0 + wv * 16 + j * 8 + rsub;
        bptr[j] = W2 + (size_t)row * I_DIM + gch;
    }

    int quad = lane >> 4, lr = lane & 15, rx = lr & 7;
    f32x4 acc[2][4] = {};

#pragma unroll
    for (int j = 0; j < 4; j++) async_copy16(aptr[j], &As[0][wv * 32 + j * 8][0]);
#pragma unroll
    for (int j = 0; j < 2; j++) async_copy16(bptr[j], &Bs[0][wv * 16 + j * 8][0]);
    __syncthreads();

    const int NK = I_DIM / 64;
    for (int k = 0; k < NK; k++) {
        int buf = k & 1;
        if (k + 1 < NK) {
            int off = (k + 1) * 64;
#pragma unroll
            for (int j = 0; j < 4; j++) async_copy16(aptr[j] + off, &As[1 - buf][wv * 32 + j * 8][0]);
#pragma unroll
            for (int j = 0; j < 2; j++) async_copy16(bptr[j] + off, &Bs[1 - buf][wv * 16 + j * 8][0]);
            __builtin_amdgcn_s_waitcnt(WAIT_VM(6));
        } else {
            __builtin_amdgcn_s_waitcnt(WAIT_VM(0));
        }
        __builtin_amdgcn_s_barrier();
#pragma unroll
        for (int ks = 0; ks < 2; ks++) {
            int co = ((ks * 4 + quad) ^ rx) * 8;
            bf16x8 a0 = *(const bf16x8*)&As[buf][wv * 32 + lr][co];
            bf16x8 a1 = *(const bf16x8*)&As[buf][wv * 32 + 16 + lr][co];
#pragma unroll
            for (int ni = 0; ni < 4; ni++) {
                bf16x8 bf = *(const bf16x8*)&Bs[buf][ni * 16 + lr][co];
                acc[0][ni] = __builtin_amdgcn_mfma_f32_16x16x32_bf16(a0, bf, acc[0][ni], 0, 0, 0);
                acc[1][ni] = __builtin_amdgcn_mfma_f32_16x16x32_bf16(a1, bf, acc[1][ni], 0, 0, 0);
            }
        }
        __builtin_amdgcn_s_barrier();
    }

#pragma unroll
    for (int mi = 0; mi < 2; mi++) {
#pragma unroll
        for (int ni = 0; ni < 4; ni++) {
#pragma unroll
            for (int rg = 0; rg < 4; rg++) {
                int ml = wv * 32 + mi * 16 + quad * 4 + rg;
                int row = m0 + ml;
                if (row < Me) {
                    int tok = toks[ml];
                    atomicAdd(&out[(size_t)tok * H_DIM + h0 + ni * 16 + lr],
                              acc[mi][ni][rg]);
                }
            }
        }
    }
}

extern "C" void kernel_launch(void* const* d_in, const int* in_sizes, int n_in,
                              void* d_out, int out_size, void* d_ws, size_t ws_size,
                              hipStream_t stream) {
    const float* x   = (const float*)d_in[0];
    const float* gw  = (const float*)d_in[1];
    const float* gb  = (const float*)d_in[2];
    const float* w1  = (const float*)d_in[3];
    const float* w2  = (const float*)d_in[4];
    const float* w3  = (const float*)d_in[5];
    const float* ws1 = (const float*)d_in[6];
    const float* ws2 = (const float*)d_in[7];
    const float* ws3 = (const float*)d_in[8];
    float* out = (float*)d_out;

    char* wsb = (char*)d_ws;
    int* counts   = (int*)(wsb + OFF_COUNTS);
    int* offsets  = (int*)(wsb + OFF_OFFSETS);
    int* tok_ids  = (int*)(wsb + OFF_TOKIDS);
    float* tok_w  = (float*)(wsb + OFF_TOKW);
    ushort* xb    = (ushort*)(wsb + OFF_XB);
    ushort* hact  = (ushort*)(wsb + OFF_HACT);
    ushort* wb1   = (ushort*)(wsb + OFF_WB1);
    ushort* wb2   = (ushort*)(wsb + OFF_WB2);
    ushort* wb3   = (ushort*)(wsb + OFF_WB3);
    ushort* wsb1  = (ushort*)(wsb + OFF_WSB1);
    ushort* wsb2  = (ushort*)(wsb + OFF_WSB2);
    ushort* wsb3  = (ushort*)(wsb + OFF_WSB3);

    hipMemsetAsync(wsb, 0, 256, stream);                       // counts
    hipMemsetAsync(d_out, 0, (size_t)out_size * 4, stream);    // zero outputs

    WcArgs wa;
    wa.src[0] = w1;  wa.dst[0] = wb1;  wa.n4[0] = N_EXP * I_DIM * H_DIM / 4;
    wa.src[1] = w2;  wa.dst[1] = wb2;  wa.n4[1] = N_EXP * H_DIM * I_DIM / 4;
    wa.src[2] = w3;  wa.dst[2] = wb3;  wa.n4[2] = N_EXP * I_DIM * H_DIM / 4;
    wa.src[3] = ws1; wa.dst[3] = wsb1; wa.n4[3] = I_DIM * H_DIM / 4;
    wa.src[4] = ws2; wa.dst[4] = wsb2; wa.n4[4] = H_DIM * I_DIM / 4;
    wa.src[5] = ws3; wa.dst[5] = wsb3; wa.n4[5] = I_DIM * H_DIM / 4;
    wa.src[6] = x;   wa.dst[6] = xb;   wa.n4[6] = N_TOK * H_DIM / 4;
    k_wconv<<<dim3(3072, 7), 256, 0, stream>>>(wa);

    k_route<<<N_TOK, 64, 0, stream>>>(x, gw, gb, counts, tok_ids, tok_w);
    k_scan<<<1, 1, 0, stream>>>(counts, offsets);
    {
        dim3 grid(N_TOK / 128, I_DIM / 64, N_EXP + 1);
        k_gateup<<<grid, 256, 0, stream>>>(xb, wb1, wb3, wsb1, wsb3, counts, offsets,
                                           tok_ids, tok_w, hact);
    }
    {
        dim3 grid(N_TOK / 128, H_DIM / 64, N_EXP + 1);
        k_down<<<grid, 256, 0, stream>>>(hact, wb2, wsb2, counts, offsets, tok_ids, out);
    }
}

// Round 4
// 428.052 us; speedup vs baseline: 1.6328x; 1.2864x over previous
//
#include <hip/hip_runtime.h>
#include <hip/hip_bf16.h>
#include <math.h>

#define N_TOK 2048
#define H_DIM 1024
#define N_EXP 16
#define I_DIM 768
#define TOPK 4
#define SCALE 2.5f
#define MAX_TILES 96

typedef __attribute__((ext_vector_type(8))) short bf16x8;
typedef __attribute__((ext_vector_type(4))) float f32x4;

// workspace layout (bytes)
#define OFF_COUNTS   0
#define OFF_OFFSETS  128
#define OFF_TILES    256
#define OFF_TOKIDS   768
#define OFF_TOKW     (OFF_TOKIDS + N_EXP*N_TOK*4)
#define OFF_XB       (OFF_TOKW + N_EXP*N_TOK*4)
#define OFF_HACT     (OFF_XB + (size_t)N_TOK*H_DIM*2)
#define OFF_WB1      (OFF_HACT + (size_t)N_TOK*(TOPK+1)*I_DIM*2)
#define OFF_WB2      (OFF_WB1 + (size_t)N_EXP*I_DIM*H_DIM*2)
#define OFF_WB3      (OFF_WB2 + (size_t)N_EXP*H_DIM*I_DIM*2)
#define OFF_WSB1     (OFF_WB3 + (size_t)N_EXP*I_DIM*H_DIM*2)
#define OFF_WSB2     (OFF_WSB1 + (size_t)I_DIM*H_DIM*2)
#define OFF_WSB3     (OFF_WSB2 + (size_t)H_DIM*I_DIM*2)
// total ~100.4 MB

__device__ __forceinline__ ushort f2bf(float f) {
    union { __hip_bfloat16 h; ushort u; } cv;
    cv.h = __float2bfloat16(f);
    return cv.u;
}
__device__ __forceinline__ unsigned pack2(float lo, float hi) {
    return (unsigned)f2bf(lo) | ((unsigned)f2bf(hi) << 16);
}
__device__ __forceinline__ void async_copy16(const void* g, void* l) {
    __builtin_amdgcn_global_load_lds(
        (const __attribute__((address_space(1))) unsigned int*)g,
        (__attribute__((address_space(3))) unsigned int*)l, 16, 0, 0);
}

// ---------------- fp32 -> bf16 bulk convert (weights + x) ----------------
struct WcArgs {
    const float* src[7];
    ushort* dst[7];
    int n4[7];
};
__global__ void k_wconv(WcArgs a) {
    int id = blockIdx.y;
    const float4* s = (const float4*)a.src[id];
    uint2* d = (uint2*)a.dst[id];
    int n4 = a.n4[id];
    int stride = gridDim.x * 256;
    for (int i = blockIdx.x * 256 + threadIdx.x; i < n4; i += stride) {
        float4 v = s[i];
        uint2 p;
        p.x = pack2(v.x, v.y);
        p.y = pack2(v.z, v.w);
        d[i] = p;
    }
}

// ---------------- routing ----------------
__global__ void k_route(const float* __restrict__ x, const float* __restrict__ gw,
                        const float* __restrict__ gb,
                        int* __restrict__ counts, int* __restrict__ tok_ids,
                        float* __restrict__ tok_w) {
    int n = blockIdx.x;
    int lane = threadIdx.x;  // 64 threads
    __shared__ float logits[N_EXP];
    float xr[16];
    const float* xrow = x + (size_t)n * H_DIM;
#pragma unroll
    for (int j = 0; j < 16; j++) xr[j] = xrow[lane + 64 * j];
    for (int e = 0; e < N_EXP; e++) {
        const float* g = gw + e * H_DIM;
        float p = 0.f;
#pragma unroll
        for (int j = 0; j < 16; j++) p += xr[j] * g[lane + 64 * j];
#pragma unroll
        for (int off = 32; off > 0; off >>= 1) p += __shfl_down(p, off);
        if (lane == 0) logits[e] = p;
    }
    __syncthreads();
    if (lane == 0) {
        float sc[N_EXP], sb[N_EXP];
        for (int e = 0; e < N_EXP; e++) {
            sc[e] = 1.f / (1.f + expf(-logits[e]));
            sb[e] = sc[e] + gb[e];
        }
        float gsc[4];
        for (int g = 0; g < 4; g++) {
            float m1 = -1e30f, m2 = -1e30f;
            for (int j = 0; j < 4; j++) {
                float v = sb[4 * g + j];
                if (v > m1) { m2 = m1; m1 = v; }
                else if (v > m2) m2 = v;
            }
            gsc[g] = m1 + m2;
        }
        int g1 = 0;
        for (int g = 1; g < 4; g++) if (gsc[g] > gsc[g1]) g1 = g;
        int g2 = -1;
        for (int g = 0; g < 4; g++) {
            if (g == g1) continue;
            if (g2 < 0 || gsc[g] > gsc[g2]) g2 = g;
        }
        bool allowed[N_EXP];
        for (int e = 0; e < N_EXP; e++) {
            int grp = e >> 2;
            allowed[e] = (grp == g1) || (grp == g2);
        }
        int chosen[TOPK];
        float wsum = 0.f;
        for (int k = 0; k < TOPK; k++) {
            int best = -1;
            for (int e = 0; e < N_EXP; e++) {
                if (!allowed[e]) continue;
                if (best < 0 || sb[e] > sb[best]) best = e;
            }
            chosen[k] = best;
            allowed[best] = false;
            wsum += sc[best];
        }
        float inv = SCALE / (wsum + 1e-20f);
        for (int k = 0; k < TOPK; k++) {
            int e = chosen[k];
            int p = atomicAdd(&counts[e], 1);
            tok_ids[e * N_TOK + p] = n;
            tok_w[e * N_TOK + p] = sc[e] * inv;
        }
    }
}

// ---------------- scan + tile-descriptor compaction ----------------
__global__ void k_scan(const int* __restrict__ counts, int* __restrict__ offsets,
                       int* __restrict__ tiles) {
    if (threadIdx.x == 0 && blockIdx.x == 0) {
        int off = 0;
        for (int e = 0; e < N_EXP; e++) { offsets[e] = off; off += counts[e]; }
        offsets[N_EXP] = off;  // shared expert base (= 8192)
        int t = 0;
        for (int e = 0; e < N_EXP; e++)
            for (int m0 = 0; m0 < counts[e]; m0 += 128)
                tiles[t++] = e | ((m0 >> 7) << 5);
        for (int m0 = 0; m0 < N_TOK; m0 += 128)
            tiles[t++] = N_EXP | ((m0 >> 7) << 5);
        for (; t < MAX_TILES; t++) tiles[t] = -1;
    }
}

// ---------------- stage A: gate/up proj + silu, gathered ----------------
// M=128, N=128 merged [w1|w3], BK=64; single-buffered m97 structure.
__launch_bounds__(256, 4)
__global__ void k_gateup(const ushort* __restrict__ xb, const ushort* __restrict__ wb1,
                         const ushort* __restrict__ wb3, const ushort* __restrict__ wsb1,
                         const ushort* __restrict__ wsb3, const int* __restrict__ counts,
                         const int* __restrict__ offsets, const int* __restrict__ tiles,
                         const int* __restrict__ tok_ids, const float* __restrict__ tok_w,
                         ushort* __restrict__ hact) {
    int desc = tiles[blockIdx.x];
    if (desc < 0) return;
    int e = desc & 31;
    int m0 = (desc >> 5) * 128;
    int i0 = blockIdx.y * 64;
    int Me = (e == N_EXP) ? N_TOK : counts[e];
    const ushort* W1 = (e == N_EXP) ? wsb1 : wb1 + (size_t)e * I_DIM * H_DIM;
    const ushort* W3 = (e == N_EXP) ? wsb3 : wb3 + (size_t)e * I_DIM * H_DIM;
    int base = offsets[e];

    __shared__ ushort As[128][64];
    __shared__ ushort Bs[128][64];   // rows 0-63: w1, rows 64-127: w3
    __shared__ float tws[128];

    int tid = threadIdx.x;
    int wv = tid >> 6, lane = tid & 63;
    int seg = lane & 7, rsub = lane >> 3;
    int gch = (seg ^ rsub) * 8;   // swizzled source chunk (element offset)

    if (tid < 128) {
        int r = m0 + tid;
        tws[tid] = (e == N_EXP) ? 1.f : ((r < Me) ? tok_w[e * N_TOK + r] : 0.f);
    }

    const ushort* aptr[4];
#pragma unroll
    for (int j = 0; j < 4; j++) {
        int gr = m0 + wv * 32 + j * 8 + rsub;
        int tok = (e == N_EXP) ? gr : ((gr < Me) ? tok_ids[e * N_TOK + gr] : 0);
        aptr[j] = xb + (size_t)tok * H_DIM + gch;
    }
    const ushort* bptr[4];
#pragma unroll
    for (int j = 0; j < 4; j++) {
        int r = wv * 32 + j * 8 + rsub;  // 0..127
        const ushort* W = (r < 64) ? (W1 + (size_t)(i0 + r) * H_DIM)
                                   : (W3 + (size_t)(i0 + r - 64) * H_DIM);
        bptr[j] = W + gch;
    }

    int quad = lane >> 4, lr = lane & 15, rx = lr & 7;
    f32x4 acc[2][8] = {};

    const int NK = H_DIM / 64;
    for (int k = 0; k < NK; k++) {
        int off = k * 64;
#pragma unroll
        for (int j = 0; j < 4; j++) async_copy16(aptr[j] + off, &As[wv * 32 + j * 8][0]);
#pragma unroll
        for (int j = 0; j < 4; j++) async_copy16(bptr[j] + off, &Bs[wv * 32 + j * 8][0]);
        __syncthreads();
#pragma unroll
        for (int ks = 0; ks < 2; ks++) {
            int co = ((ks * 4 + quad) ^ rx) * 8;  // swizzled read chunk
            bf16x8 a0 = *(const bf16x8*)&As[wv * 32 + lr][co];
            bf16x8 a1 = *(const bf16x8*)&As[wv * 32 + 16 + lr][co];
#pragma unroll
            for (int ni = 0; ni < 8; ni++) {
                bf16x8 bf = *(const bf16x8*)&Bs[ni * 16 + lr][co];
                acc[0][ni] = __builtin_amdgcn_mfma_f32_16x16x32_bf16(a0, bf, acc[0][ni], 0, 0, 0);
                acc[1][ni] = __builtin_amdgcn_mfma_f32_16x16x32_bf16(a1, bf, acc[1][ni], 0, 0, 0);
            }
        }
        __syncthreads();
    }

    // epilogue: g = acc[.][0..3], u = acc[.][4..7] (same lane) -> silu(g)*u*tw
#pragma unroll
    for (int mi = 0; mi < 2; mi++) {
#pragma unroll
        for (int ni = 0; ni < 4; ni++) {
            f32x4 g = acc[mi][ni];
            f32x4 u = acc[mi][ni + 4];
#pragma unroll
            for (int rg = 0; rg < 4; rg++) {
                int ml = wv * 32 + mi * 16 + quad * 4 + rg;
                int row = m0 + ml;
                if (row < Me) {
                    float gg = g[rg], uu = u[rg];
                    float act = (gg / (1.f + expf(-gg))) * uu * tws[ml];
                    hact[(size_t)(base + row) * I_DIM + i0 + ni * 16 + lr] = f2bf(act);
                }
            }
        }
    }
}

// ---------------- stage B: down proj + scatter-add ----------------
// M=128 slots, N=128 of H, BK=64 over I=768; same single-buffer structure.
__launch_bounds__(256, 4)
__global__ void k_down(const ushort* __restrict__ hact, const ushort* __restrict__ wb2,
                       const ushort* __restrict__ wsb2, const int* __restrict__ counts,
                       const int* __restrict__ offsets, const int* __restrict__ tiles,
                       const int* __restrict__ tok_ids, float* __restrict__ out) {
    int desc = tiles[blockIdx.x];
    if (desc < 0) return;
    int e = desc & 31;
    int m0 = (desc >> 5) * 128;
    int h0 = blockIdx.y * 128;
    int Me = (e == N_EXP) ? N_TOK : counts[e];
    const ushort* W2 = (e == N_EXP) ? wsb2 : wb2 + (size_t)e * H_DIM * I_DIM;
    int base = offsets[e];

    __shared__ ushort As[128][64];
    __shared__ ushort Bs[128][64];
    __shared__ int toks[128];

    int tid = threadIdx.x;
    int wv = tid >> 6, lane = tid & 63;
    int seg = lane & 7, rsub = lane >> 3;
    int gch = (seg ^ rsub) * 8;

    if (tid < 128) {
        int r = m0 + tid;
        toks[tid] = (e == N_EXP) ? r : ((r < Me) ? tok_ids[e * N_TOK + r] : 0);
    }

    const ushort* aptr[4];
#pragma unroll
    for (int j = 0; j < 4; j++) {
        int row = wv * 32 + j * 8 + rsub;
        aptr[j] = hact + (size_t)(base + m0 + row) * I_DIM + gch;
    }
    const ushort* bptr[4];
#pragma unroll
    for (int j = 0; j < 4; j++) {
        int r = wv * 32 + j * 8 + rsub;
        bptr[j] = W2 + (size_t)(h0 + r) * I_DIM + gch;
    }

    int quad = lane >> 4, lr = lane & 15, rx = lr & 7;
    f32x4 acc[2][8] = {};

    const int NK = I_DIM / 64;
    for (int k = 0; k < NK; k++) {
        int off = k * 64;
#pragma unroll
        for (int j = 0; j < 4; j++) async_copy16(aptr[j] + off, &As[wv * 32 + j * 8][0]);
#pragma unroll
        for (int j = 0; j < 4; j++) async_copy16(bptr[j] + off, &Bs[wv * 32 + j * 8][0]);
        __syncthreads();
#pragma unroll
        for (int ks = 0; ks < 2; ks++) {
            int co = ((ks * 4 + quad) ^ rx) * 8;
            bf16x8 a0 = *(const bf16x8*)&As[wv * 32 + lr][co];
            bf16x8 a1 = *(const bf16x8*)&As[wv * 32 + 16 + lr][co];
#pragma unroll
            for (int ni = 0; ni < 8; ni++) {
                bf16x8 bf = *(const bf16x8*)&Bs[ni * 16 + lr][co];
                acc[0][ni] = __builtin_amdgcn_mfma_f32_16x16x32_bf16(a0, bf, acc[0][ni], 0, 0, 0);
                acc[1][ni] = __builtin_amdgcn_mfma_f32_16x16x32_bf16(a1, bf, acc[1][ni], 0, 0, 0);
            }
        }
        __syncthreads();
    }

#pragma unroll
    for (int mi = 0; mi < 2; mi++) {
#pragma unroll
        for (int ni = 0; ni < 8; ni++) {
#pragma unroll
            for (int rg = 0; rg < 4; rg++) {
                int ml = wv * 32 + mi * 16 + quad * 4 + rg;
                int row = m0 + ml;
                if (row < Me) {
                    int tok = toks[ml];
                    atomicAdd(&out[(size_t)tok * H_DIM + h0 + ni * 16 + lr],
                              acc[mi][ni][rg]);
                }
            }
        }
    }
}

extern "C" void kernel_launch(void* const* d_in, const int* in_sizes, int n_in,
                              void* d_out, int out_size, void* d_ws, size_t ws_size,
                              hipStream_t stream) {
    const float* x   = (const float*)d_in[0];
    const float* gw  = (const float*)d_in[1];
    const float* gb  = (const float*)d_in[2];
    const float* w1  = (const float*)d_in[3];
    const float* w2  = (const float*)d_in[4];
    const float* w3  = (const float*)d_in[5];
    const float* ws1 = (const float*)d_in[6];
    const float* ws2 = (const float*)d_in[7];
    const float* ws3 = (const float*)d_in[8];
    float* out = (float*)d_out;

    char* wsb = (char*)d_ws;
    int* counts   = (int*)(wsb + OFF_COUNTS);
    int* offsets  = (int*)(wsb + OFF_OFFSETS);
    int* tiles    = (int*)(wsb + OFF_TILES);
    int* tok_ids  = (int*)(wsb + OFF_TOKIDS);
    float* tok_w  = (float*)(wsb + OFF_TOKW);
    ushort* xb    = (ushort*)(wsb + OFF_XB);
    ushort* hact  = (ushort*)(wsb + OFF_HACT);
    ushort* wb1   = (ushort*)(wsb + OFF_WB1);
    ushort* wb2   = (ushort*)(wsb + OFF_WB2);
    ushort* wb3   = (ushort*)(wsb + OFF_WB3);
    ushort* wsb1  = (ushort*)(wsb + OFF_WSB1);
    ushort* wsb2  = (ushort*)(wsb + OFF_WSB2);
    ushort* wsb3  = (ushort*)(wsb + OFF_WSB3);

    hipMemsetAsync(wsb, 0, 128, stream);                       // counts
    hipMemsetAsync(d_out, 0, (size_t)out_size * 4, stream);    // zero outputs

    WcArgs wa;
    wa.src[0] = w1;  wa.dst[0] = wb1;  wa.n4[0] = N_EXP * I_DIM * H_DIM / 4;
    wa.src[1] = w2;  wa.dst[1] = wb2;  wa.n4[1] = N_EXP * H_DIM * I_DIM / 4;
    wa.src[2] = w3;  wa.dst[2] = wb3;  wa.n4[2] = N_EXP * I_DIM * H_DIM / 4;
    wa.src[3] = ws1; wa.dst[3] = wsb1; wa.n4[3] = I_DIM * H_DIM / 4;
    wa.src[4] = ws2; wa.dst[4] = wsb2; wa.n4[4] = H_DIM * I_DIM / 4;
    wa.src[5] = ws3; wa.dst[5] = wsb3; wa.n4[5] = I_DIM * H_DIM / 4;
    wa.src[6] = x;   wa.dst[6] = xb;   wa.n4[6] = N_TOK * H_DIM / 4;
    k_wconv<<<dim3(3072, 7), 256, 0, stream>>>(wa);

    k_route<<<N_TOK, 64, 0, stream>>>(x, gw, gb, counts, tok_ids, tok_w);
    k_scan<<<1, 1, 0, stream>>>(counts, offsets, tiles);
    {
        dim3 grid(MAX_TILES, I_DIM / 64);
        k_gateup<<<grid, 256, 0, stream>>>(xb, wb1, wb3, wsb1, wsb3, counts, offsets,
                                           tiles, tok_ids, tok_w, hact);
    }
    {
        dim3 grid(MAX_TILES, H_DIM / 128);
        k_down<<<grid, 256, 0, stream>>>(hact, wb2, wsb2, counts, offsets, tiles,
                                         tok_ids, out);
    }
}

// Round 6
// 394.028 us; speedup vs baseline: 1.7738x; 1.0863x over previous
//
#include <hip/hip_runtime.h>
#include <hip/hip_bf16.h>
#include <math.h>

#define N_TOK 2048
#define H_DIM 1024
#define N_EXP 16
#define I_DIM 768
#define TOPK 4
#define SCALE 2.5f
#define MAX_TILES 96

typedef __attribute__((ext_vector_type(8))) short bf16x8;
typedef __attribute__((ext_vector_type(4))) float f32x4;

// workspace layout (bytes)
#define OFF_COUNTS   0
#define OFF_OFFSETS  128
#define OFF_TILES    256
#define OFF_TOKIDS   768
#define OFF_TOKW     (OFF_TOKIDS + N_EXP*N_TOK*4)
#define OFF_XB       (OFF_TOKW + N_EXP*N_TOK*4)
#define OFF_HACT     (OFF_XB + (size_t)N_TOK*H_DIM*2)
#define OFF_WB1      (OFF_HACT + (size_t)N_TOK*(TOPK+1)*I_DIM*2)
#define OFF_WB2      (OFF_WB1 + (size_t)N_EXP*I_DIM*H_DIM*2)
#define OFF_WB3      (OFF_WB2 + (size_t)N_EXP*H_DIM*I_DIM*2)
#define OFF_WSB1     (OFF_WB3 + (size_t)N_EXP*I_DIM*H_DIM*2)
#define OFF_WSB2     (OFF_WSB1 + (size_t)I_DIM*H_DIM*2)
#define OFF_WSB3     (OFF_WSB2 + (size_t)H_DIM*I_DIM*2)
// total ~100.4 MB

__device__ __forceinline__ ushort f2bf(float f) {
    union { __hip_bfloat16 h; ushort u; } cv;
    cv.h = __float2bfloat16(f);
    return cv.u;
}
__device__ __forceinline__ unsigned pack2(float lo, float hi) {
    return (unsigned)f2bf(lo) | ((unsigned)f2bf(hi) << 16);
}
__device__ __forceinline__ void async_copy16(const void* g, void* l) {
    __builtin_amdgcn_global_load_lds(
        (const __attribute__((address_space(1))) unsigned int*)g,
        (__attribute__((address_space(3))) unsigned int*)l, 16, 0, 0);
}

// ---------------- fp32 -> bf16 bulk convert (weights + x) ----------------
struct WcArgs {
    const float* src[7];
    ushort* dst[7];
    int n4[7];
};
__global__ void k_wconv(WcArgs a) {
    int id = blockIdx.y;
    const float4* s = (const float4*)a.src[id];
    uint2* d = (uint2*)a.dst[id];
    int n4 = a.n4[id];
    int stride = gridDim.x * 256;
    for (int i = blockIdx.x * 256 + threadIdx.x; i < n4; i += stride) {
        float4 v = s[i];
        uint2 p;
        p.x = pack2(v.x, v.y);
        p.y = pack2(v.z, v.w);
        d[i] = p;
    }
}

// ---------------- routing: 16 tokens/block, thread = (tok,expert) ----------------
// gate_w is 64 KB fp32 -> L1/L2-hot; read directly through cache (NO big LDS:
// >64 KB/workgroup static LDS breaks graph capture -> silent launch drop).
__launch_bounds__(256)
__global__ void k_route(const float* __restrict__ x, const float* __restrict__ gw,
                        const float* __restrict__ gb,
                        int* __restrict__ counts, int* __restrict__ tok_ids,
                        float* __restrict__ tok_w) {
    __shared__ float lgs[16][N_EXP + 1];
    int tid = threadIdx.x;
    int tok0 = blockIdx.x * 16;
    int tok = tid >> 4, e = tid & 15;

    const float4* xr = (const float4*)(x + (size_t)(tok0 + tok) * H_DIM);
    const float4* wr = (const float4*)(gw + (size_t)e * H_DIM);
    float acc = 0.f;
#pragma unroll 8
    for (int k = 0; k < H_DIM / 4; k++) {
        float4 xv = xr[k];
        float4 wv = wr[k];
        acc += xv.x * wv.x + xv.y * wv.y + xv.z * wv.z + xv.w * wv.w;
    }
    lgs[tok][e] = acc;
    __syncthreads();

    if (tid < 16) {
        int n = tok0 + tid;
        float sc[N_EXP], sb[N_EXP];
        for (int ee = 0; ee < N_EXP; ee++) {
            float l = lgs[tid][ee];
            sc[ee] = 1.f / (1.f + expf(-l));
            sb[ee] = sc[ee] + gb[ee];
        }
        float gsc[4];
        for (int g = 0; g < 4; g++) {
            float m1 = -1e30f, m2 = -1e30f;
            for (int j = 0; j < 4; j++) {
                float v = sb[4 * g + j];
                if (v > m1) { m2 = m1; m1 = v; }
                else if (v > m2) m2 = v;
            }
            gsc[g] = m1 + m2;
        }
        int g1 = 0;
        for (int g = 1; g < 4; g++) if (gsc[g] > gsc[g1]) g1 = g;
        int g2 = -1;
        for (int g = 0; g < 4; g++) {
            if (g == g1) continue;
            if (g2 < 0 || gsc[g] > gsc[g2]) g2 = g;
        }
        bool allowed[N_EXP];
        for (int ee = 0; ee < N_EXP; ee++) {
            int grp = ee >> 2;
            allowed[ee] = (grp == g1) || (grp == g2);
        }
        int chosen[TOPK];
        float wsum = 0.f;
        for (int k = 0; k < TOPK; k++) {
            int best = -1;
            for (int ee = 0; ee < N_EXP; ee++) {
                if (!allowed[ee]) continue;
                if (best < 0 || sb[ee] > sb[best]) best = ee;
            }
            chosen[k] = best;
            allowed[best] = false;
            wsum += sc[best];
        }
        float inv = SCALE / (wsum + 1e-20f);
        for (int k = 0; k < TOPK; k++) {
            int ee = chosen[k];
            int p = atomicAdd(&counts[ee], 1);
            tok_ids[ee * N_TOK + p] = n;
            tok_w[ee * N_TOK + p] = sc[ee] * inv;
        }
    }
}

// ---------------- scan + tile-descriptor compaction ----------------
__global__ void k_scan(const int* __restrict__ counts, int* __restrict__ offsets,
                       int* __restrict__ tiles) {
    if (threadIdx.x == 0 && blockIdx.x == 0) {
        int off = 0;
        for (int e = 0; e < N_EXP; e++) { offsets[e] = off; off += counts[e]; }
        offsets[N_EXP] = off;  // shared expert base (= 8192)
        int t = 0;
        for (int e = 0; e < N_EXP; e++)
            for (int m0 = 0; m0 < counts[e]; m0 += 128)
                tiles[t++] = e | ((m0 >> 7) << 5);
        for (int m0 = 0; m0 < N_TOK; m0 += 128)
            tiles[t++] = N_EXP | ((m0 >> 7) << 5);
        for (; t < MAX_TILES; t++) tiles[t] = -1;
    }
}

// ---------------- stage A: gate/up proj + silu, gathered ----------------
// M=128, N=128 merged [w1|w3], BK=64; single-buffered m97 structure.
__launch_bounds__(256, 4)
__global__ void k_gateup(const ushort* __restrict__ xb, const ushort* __restrict__ wb1,
                         const ushort* __restrict__ wb3, const ushort* __restrict__ wsb1,
                         const ushort* __restrict__ wsb3, const int* __restrict__ counts,
                         const int* __restrict__ offsets, const int* __restrict__ tiles,
                         const int* __restrict__ tok_ids, const float* __restrict__ tok_w,
                         ushort* __restrict__ hact) {
    int desc = tiles[blockIdx.x];
    if (desc < 0) return;
    int e = desc & 31;
    int m0 = (desc >> 5) * 128;
    int i0 = blockIdx.y * 64;
    int Me = (e == N_EXP) ? N_TOK : counts[e];
    const ushort* W1 = (e == N_EXP) ? wsb1 : wb1 + (size_t)e * I_DIM * H_DIM;
    const ushort* W3 = (e == N_EXP) ? wsb3 : wb3 + (size_t)e * I_DIM * H_DIM;
    int base = offsets[e];

    __shared__ ushort As[128][64];
    __shared__ ushort Bs[128][64];   // rows 0-63: w1, rows 64-127: w3
    __shared__ float tws[128];

    int tid = threadIdx.x;
    int wv = tid >> 6, lane = tid & 63;
    int seg = lane & 7, rsub = lane >> 3;
    int gch = (seg ^ rsub) * 8;   // swizzled source chunk (element offset)

    if (tid < 128) {
        int r = m0 + tid;
        tws[tid] = (e == N_EXP) ? 1.f : ((r < Me) ? tok_w[e * N_TOK + r] : 0.f);
    }

    const ushort* aptr[4];
#pragma unroll
    for (int j = 0; j < 4; j++) {
        int gr = m0 + wv * 32 + j * 8 + rsub;
        int tok = (e == N_EXP) ? gr : ((gr < Me) ? tok_ids[e * N_TOK + gr] : 0);
        aptr[j] = xb + (size_t)tok * H_DIM + gch;
    }
    const ushort* bptr[4];
#pragma unroll
    for (int j = 0; j < 4; j++) {
        int r = wv * 32 + j * 8 + rsub;  // 0..127
        const ushort* W = (r < 64) ? (W1 + (size_t)(i0 + r) * H_DIM)
                                   : (W3 + (size_t)(i0 + r - 64) * H_DIM);
        bptr[j] = W + gch;
    }

    int quad = lane >> 4, lr = lane & 15, rx = lr & 7;
    f32x4 acc[2][8] = {};

    const int NK = H_DIM / 64;
    for (int k = 0; k < NK; k++) {
        int off = k * 64;
#pragma unroll
        for (int j = 0; j < 4; j++) async_copy16(aptr[j] + off, &As[wv * 32 + j * 8][0]);
#pragma unroll
        for (int j = 0; j < 4; j++) async_copy16(bptr[j] + off, &Bs[wv * 32 + j * 8][0]);
        __syncthreads();
#pragma unroll
        for (int ks = 0; ks < 2; ks++) {
            int co = ((ks * 4 + quad) ^ rx) * 8;  // swizzled read chunk
            bf16x8 a0 = *(const bf16x8*)&As[wv * 32 + lr][co];
            bf16x8 a1 = *(const bf16x8*)&As[wv * 32 + 16 + lr][co];
#pragma unroll
            for (int ni = 0; ni < 8; ni++) {
                bf16x8 bf = *(const bf16x8*)&Bs[ni * 16 + lr][co];
                acc[0][ni] = __builtin_amdgcn_mfma_f32_16x16x32_bf16(a0, bf, acc[0][ni], 0, 0, 0);
                acc[1][ni] = __builtin_amdgcn_mfma_f32_16x16x32_bf16(a1, bf, acc[1][ni], 0, 0, 0);
            }
        }
        __syncthreads();
    }

    // epilogue: g = acc[.][0..3], u = acc[.][4..7] (same lane) -> silu(g)*u*tw
#pragma unroll
    for (int mi = 0; mi < 2; mi++) {
#pragma unroll
        for (int ni = 0; ni < 4; ni++) {
            f32x4 g = acc[mi][ni];
            f32x4 u = acc[mi][ni + 4];
#pragma unroll
            for (int rg = 0; rg < 4; rg++) {
                int ml = wv * 32 + mi * 16 + quad * 4 + rg;
                int row = m0 + ml;
                if (row < Me) {
                    float gg = g[rg], uu = u[rg];
                    float act = (gg / (1.f + expf(-gg))) * uu * tws[ml];
                    hact[(size_t)(base + row) * I_DIM + i0 + ni * 16 + lr] = f2bf(act);
                }
            }
        }
    }
}

// ---------------- stage B: down proj + scatter-add ----------------
// M=128 slots, N=128 of H, BK=64 over I=768; same single-buffer structure.
__launch_bounds__(256, 4)
__global__ void k_down(const ushort* __restrict__ hact, const ushort* __restrict__ wb2,
                       const ushort* __restrict__ wsb2, const int* __restrict__ counts,
                       const int* __restrict__ offsets, const int* __restrict__ tiles,
                       const int* __restrict__ tok_ids, float* __restrict__ out) {
    int desc = tiles[blockIdx.x];
    if (desc < 0) return;
    int e = desc & 31;
    int m0 = (desc >> 5) * 128;
    int h0 = blockIdx.y * 128;
    int Me = (e == N_EXP) ? N_TOK : counts[e];
    const ushort* W2 = (e == N_EXP) ? wsb2 : wb2 + (size_t)e * H_DIM * I_DIM;
    int base = offsets[e];

    __shared__ ushort As[128][64];
    __shared__ ushort Bs[128][64];
    __shared__ int toks[128];

    int tid = threadIdx.x;
    int wv = tid >> 6, lane = tid & 63;
    int seg = lane & 7, rsub = lane >> 3;
    int gch = (seg ^ rsub) * 8;

    if (tid < 128) {
        int r = m0 + tid;
        toks[tid] = (e == N_EXP) ? r : ((r < Me) ? tok_ids[e * N_TOK + r] : 0);
    }

    const ushort* aptr[4];
#pragma unroll
    for (int j = 0; j < 4; j++) {
        int row = wv * 32 + j * 8 + rsub;
        aptr[j] = hact + (size_t)(base + m0 + row) * I_DIM + gch;
    }
    const ushort* bptr[4];
#pragma unroll
    for (int j = 0; j < 4; j++) {
        int r = wv * 32 + j * 8 + rsub;
        bptr[j] = W2 + (size_t)(h0 + r) * I_DIM + gch;
    }

    int quad = lane >> 4, lr = lane & 15, rx = lr & 7;
    f32x4 acc[2][8] = {};

    const int NK = I_DIM / 64;
    for (int k = 0; k < NK; k++) {
        int off = k * 64;
#pragma unroll
        for (int j = 0; j < 4; j++) async_copy16(aptr[j] + off, &As[wv * 32 + j * 8][0]);
#pragma unroll
        for (int j = 0; j < 4; j++) async_copy16(bptr[j] + off, &Bs[wv * 32 + j * 8][0]);
        __syncthreads();
#pragma unroll
        for (int ks = 0; ks < 2; ks++) {
            int co = ((ks * 4 + quad) ^ rx) * 8;
            bf16x8 a0 = *(const bf16x8*)&As[wv * 32 + lr][co];
            bf16x8 a1 = *(const bf16x8*)&As[wv * 32 + 16 + lr][co];
#pragma unroll
            for (int ni = 0; ni < 8; ni++) {
                bf16x8 bf = *(const bf16x8*)&Bs[ni * 16 + lr][co];
                acc[0][ni] = __builtin_amdgcn_mfma_f32_16x16x32_bf16(a0, bf, acc[0][ni], 0, 0, 0);
                acc[1][ni] = __builtin_amdgcn_mfma_f32_16x16x32_bf16(a1, bf, acc[1][ni], 0, 0, 0);
            }
        }
        __syncthreads();
    }

#pragma unroll
    for (int mi = 0; mi < 2; mi++) {
#pragma unroll
        for (int ni = 0; ni < 8; ni++) {
#pragma unroll
            for (int rg = 0; rg < 4; rg++) {
                int ml = wv * 32 + mi * 16 + quad * 4 + rg;
                int row = m0 + ml;
                if (row < Me) {
                    int tok = toks[ml];
                    atomicAdd(&out[(size_t)tok * H_DIM + h0 + ni * 16 + lr],
                              acc[mi][ni][rg]);
                }
            }
        }
    }
}

extern "C" void kernel_launch(void* const* d_in, const int* in_sizes, int n_in,
                              void* d_out, int out_size, void* d_ws, size_t ws_size,
                              hipStream_t stream) {
    const float* x   = (const float*)d_in[0];
    const float* gw  = (const float*)d_in[1];
    const float* gb  = (const float*)d_in[2];
    const float* w1  = (const float*)d_in[3];
    const float* w2  = (const float*)d_in[4];
    const float* w3  = (const float*)d_in[5];
    const float* ws1 = (const float*)d_in[6];
    const float* ws2 = (const float*)d_in[7];
    const float* ws3 = (const float*)d_in[8];
    float* out = (float*)d_out;

    char* wsb = (char*)d_ws;
    int* counts   = (int*)(wsb + OFF_COUNTS);
    int* offsets  = (int*)(wsb + OFF_OFFSETS);
    int* tiles    = (int*)(wsb + OFF_TILES);
    int* tok_ids  = (int*)(wsb + OFF_TOKIDS);
    float* tok_w  = (float*)(wsb + OFF_TOKW);
    ushort* xb    = (ushort*)(wsb + OFF_XB);
    ushort* hact  = (ushort*)(wsb + OFF_HACT);
    ushort* wb1   = (ushort*)(wsb + OFF_WB1);
    ushort* wb2   = (ushort*)(wsb + OFF_WB2);
    ushort* wb3   = (ushort*)(wsb + OFF_WB3);
    ushort* wsb1  = (ushort*)(wsb + OFF_WSB1);
    ushort* wsb2  = (ushort*)(wsb + OFF_WSB2);
    ushort* wsb3  = (ushort*)(wsb + OFF_WSB3);

    hipMemsetAsync(wsb, 0, 128, stream);                       // counts
    hipMemsetAsync(d_out, 0, (size_t)out_size * 4, stream);    // zero outputs

    WcArgs wa;
    wa.src[0] = w1;  wa.dst[0] = wb1;  wa.n4[0] = N_EXP * I_DIM * H_DIM / 4;
    wa.src[1] = w2;  wa.dst[1] = wb2;  wa.n4[1] = N_EXP * H_DIM * I_DIM / 4;
    wa.src[2] = w3;  wa.dst[2] = wb3;  wa.n4[2] = N_EXP * I_DIM * H_DIM / 4;
    wa.src[3] = ws1; wa.dst[3] = wsb1; wa.n4[3] = I_DIM * H_DIM / 4;
    wa.src[4] = ws2; wa.dst[4] = wsb2; wa.n4[4] = H_DIM * I_DIM / 4;
    wa.src[5] = ws3; wa.dst[5] = wsb3; wa.n4[5] = I_DIM * H_DIM / 4;
    wa.src[6] = x;   wa.dst[6] = xb;   wa.n4[6] = N_TOK * H_DIM / 4;
    k_wconv<<<dim3(3072, 7), 256, 0, stream>>>(wa);

    k_route<<<N_TOK / 16, 256, 0, stream>>>(x, gw, gb, counts, tok_ids, tok_w);
    k_scan<<<1, 1, 0, stream>>>(counts, offsets, tiles);
    {
        dim3 grid(MAX_TILES, I_DIM / 64);
        k_gateup<<<grid, 256, 0, stream>>>(xb, wb1, wb3, wsb1, wsb3, counts, offsets,
                                           tiles, tok_ids, tok_w, hact);
    }
    {
        dim3 grid(MAX_TILES, H_DIM / 128);
        k_down<<<grid, 256, 0, stream>>>(hact, wb2, wsb2, counts, offsets, tiles,
                                         tok_ids, out);
    }
}

// Round 7
// 363.460 us; speedup vs baseline: 1.9230x; 1.0841x over previous
//
#include <hip/hip_runtime.h>
#include <hip/hip_bf16.h>
#include <math.h>

#define N_TOK 2048
#define H_DIM 1024
#define N_EXP 16
#define I_DIM 768
#define TOPK 4
#define SCALE 2.5f
#define MAX_TILES 96

typedef __attribute__((ext_vector_type(8))) short bf16x8;
typedef __attribute__((ext_vector_type(4))) float f32x4;

// workspace layout (bytes)
#define OFF_COUNTS   0
#define OFF_OFFSETS  128
#define OFF_TILES    256
#define OFF_TOKIDS   768
#define OFF_TOKW     (OFF_TOKIDS + N_EXP*N_TOK*4)
#define OFF_XB       (OFF_TOKW + N_EXP*N_TOK*4)
#define OFF_HACT     (OFF_XB + (size_t)N_TOK*H_DIM*2)
#define OFF_WB1      (OFF_HACT + (size_t)N_TOK*(TOPK+1)*I_DIM*2)
#define OFF_WB2      (OFF_WB1 + (size_t)N_EXP*I_DIM*H_DIM*2)
#define OFF_WB3      (OFF_WB2 + (size_t)N_EXP*H_DIM*I_DIM*2)
#define OFF_WSB1     (OFF_WB3 + (size_t)N_EXP*I_DIM*H_DIM*2)
#define OFF_WSB2     (OFF_WSB1 + (size_t)I_DIM*H_DIM*2)
#define OFF_WSB3     (OFF_WSB2 + (size_t)H_DIM*I_DIM*2)
#define OFF_GWT      (OFF_WSB3 + (size_t)I_DIM*H_DIM*2)
// total ~100.5 MB

__device__ __forceinline__ ushort f2bf(float f) {
    union { __hip_bfloat16 h; ushort u; } cv;
    cv.h = __float2bfloat16(f);
    return cv.u;
}
__device__ __forceinline__ unsigned pack2(float lo, float hi) {
    return (unsigned)f2bf(lo) | ((unsigned)f2bf(hi) << 16);
}
__device__ __forceinline__ void async_copy16(const void* g, void* l) {
    __builtin_amdgcn_global_load_lds(
        (const __attribute__((address_space(1))) unsigned int*)g,
        (__attribute__((address_space(3))) unsigned int*)l, 16, 0, 0);
}

// ---------------- fp32 -> bf16 bulk convert (weights + x) ----------------
struct WcArgs {
    const float* src[7];
    ushort* dst[7];
    int n4[7];
};
__global__ void k_wconv(WcArgs a) {
    int id = blockIdx.y;
    const float4* s = (const float4*)a.src[id];
    uint2* d = (uint2*)a.dst[id];
    int n4 = a.n4[id];
    int stride = gridDim.x * 256;
    for (int i = blockIdx.x * 256 + threadIdx.x; i < n4; i += stride) {
        float4 v = s[i];
        uint2 p;
        p.x = pack2(v.x, v.y);
        p.y = pack2(v.z, v.w);
        d[i] = p;
    }
}

// ---------------- gate_w transpose: gwT[k][e] (fp32, 64 KB, stays cache-hot) ----------------
__global__ void k_gwt(const float* __restrict__ gw, float* __restrict__ gwT) {
    int i = blockIdx.x * 256 + threadIdx.x;   // 16384 elements
    int k = i >> 4, e = i & 15;
    gwT[i] = gw[e * H_DIM + k];
}

// ---------------- routing: 1 wave/token, lane = (kslice, expert) ----------------
// fp32 math throughout (bf16 logits risk top-k flips near ties).
__launch_bounds__(256)
__global__ void k_route(const float* __restrict__ x, const float* __restrict__ gwT,
                        const float* __restrict__ gb,
                        int* __restrict__ counts, int* __restrict__ tok_ids,
                        float* __restrict__ tok_w) {
    __shared__ float lgs[4][N_EXP + 1];
    int tid = threadIdx.x;
    int wv = tid >> 6, lane = tid & 63;
    int e = lane & 15, ks = lane >> 4;        // expert, k-slice (4 x 256)
    int n = blockIdx.x * 4 + wv;

    const float* xr = x + (size_t)n * H_DIM + ks * 256;      // broadcast over 16 e-lanes
    const float* wr = gwT + ks * 256 * N_EXP + e;            // contiguous over e-lanes
    float a0 = 0.f, a1 = 0.f, a2 = 0.f, a3 = 0.f;
#pragma unroll 8
    for (int k = 0; k < 256; k += 4) {
        float4 xv = *(const float4*)(xr + k);
        a0 += xv.x * wr[(k + 0) * N_EXP];
        a1 += xv.y * wr[(k + 1) * N_EXP];
        a2 += xv.z * wr[(k + 2) * N_EXP];
        a3 += xv.w * wr[(k + 3) * N_EXP];
    }
    float acc = (a0 + a1) + (a2 + a3);
    acc += __shfl_xor(acc, 16);   // fold k-slices
    acc += __shfl_xor(acc, 32);
    if (lane < 16) lgs[wv][lane] = acc;
    __syncthreads();

    if (tid < 4) {
        int n2 = blockIdx.x * 4 + tid;
        float sc[N_EXP], sb[N_EXP];
        for (int ee = 0; ee < N_EXP; ee++) {
            float l = lgs[tid][ee];
            sc[ee] = 1.f / (1.f + expf(-l));
            sb[ee] = sc[ee] + gb[ee];
        }
        float gsc[4];
        for (int g = 0; g < 4; g++) {
            float m1 = -1e30f, m2 = -1e30f;
            for (int j = 0; j < 4; j++) {
                float v = sb[4 * g + j];
                if (v > m1) { m2 = m1; m1 = v; }
                else if (v > m2) m2 = v;
            }
            gsc[g] = m1 + m2;
        }
        int g1 = 0;
        for (int g = 1; g < 4; g++) if (gsc[g] > gsc[g1]) g1 = g;
        int g2 = -1;
        for (int g = 0; g < 4; g++) {
            if (g == g1) continue;
            if (g2 < 0 || gsc[g] > gsc[g2]) g2 = g;
        }
        bool allowed[N_EXP];
        for (int ee = 0; ee < N_EXP; ee++) {
            int grp = ee >> 2;
            allowed[ee] = (grp == g1) || (grp == g2);
        }
        int chosen[TOPK];
        float wsum = 0.f;
        for (int k = 0; k < TOPK; k++) {
            int best = -1;
            for (int ee = 0; ee < N_EXP; ee++) {
                if (!allowed[ee]) continue;
                if (best < 0 || sb[ee] > sb[best]) best = ee;
            }
            chosen[k] = best;
            allowed[best] = false;
            wsum += sc[best];
        }
        float inv = SCALE / (wsum + 1e-20f);
        for (int k = 0; k < TOPK; k++) {
            int ee = chosen[k];
            int p = atomicAdd(&counts[ee], 1);
            tok_ids[ee * N_TOK + p] = n2;
            tok_w[ee * N_TOK + p] = sc[ee] * inv;
        }
    }
}

// ---------------- scan + tile-descriptor compaction ----------------
__global__ void k_scan(const int* __restrict__ counts, int* __restrict__ offsets,
                       int* __restrict__ tiles) {
    if (threadIdx.x == 0 && blockIdx.x == 0) {
        int off = 0;
        for (int e = 0; e < N_EXP; e++) { offsets[e] = off; off += counts[e]; }
        offsets[N_EXP] = off;  // shared expert base (= 8192)
        int t = 0;
        for (int e = 0; e < N_EXP; e++)
            for (int m0 = 0; m0 < counts[e]; m0 += 128)
                tiles[t++] = e | ((m0 >> 7) << 5);
        for (int m0 = 0; m0 < N_TOK; m0 += 128)
            tiles[t++] = N_EXP | ((m0 >> 7) << 5);
        for (; t < MAX_TILES; t++) tiles[t] = -1;
    }
}

// ---------------- stage A: gate/up proj + silu, gathered ----------------
// M=128, N=128 merged [w1|w3], BK=64; single-buffered m97 structure.
__launch_bounds__(256, 4)
__global__ void k_gateup(const ushort* __restrict__ xb, const ushort* __restrict__ wb1,
                         const ushort* __restrict__ wb3, const ushort* __restrict__ wsb1,
                         const ushort* __restrict__ wsb3, const int* __restrict__ counts,
                         const int* __restrict__ offsets, const int* __restrict__ tiles,
                         const int* __restrict__ tok_ids, const float* __restrict__ tok_w,
                         ushort* __restrict__ hact) {
    int desc = tiles[blockIdx.x];
    if (desc < 0) return;
    int e = desc & 31;
    int m0 = (desc >> 5) * 128;
    int i0 = blockIdx.y * 64;
    int Me = (e == N_EXP) ? N_TOK : counts[e];
    const ushort* W1 = (e == N_EXP) ? wsb1 : wb1 + (size_t)e * I_DIM * H_DIM;
    const ushort* W3 = (e == N_EXP) ? wsb3 : wb3 + (size_t)e * I_DIM * H_DIM;
    int base = offsets[e];

    __shared__ ushort As[128][64];
    __shared__ ushort Bs[128][64];   // rows 0-63: w1, rows 64-127: w3
    __shared__ float tws[128];

    int tid = threadIdx.x;
    int wv = tid >> 6, lane = tid & 63;
    int seg = lane & 7, rsub = lane >> 3;
    int gch = (seg ^ rsub) * 8;   // swizzled source chunk (element offset)

    if (tid < 128) {
        int r = m0 + tid;
        tws[tid] = (e == N_EXP) ? 1.f : ((r < Me) ? tok_w[e * N_TOK + r] : 0.f);
    }

    const ushort* aptr[4];
#pragma unroll
    for (int j = 0; j < 4; j++) {
        int gr = m0 + wv * 32 + j * 8 + rsub;
        int tok = (e == N_EXP) ? gr : ((gr < Me) ? tok_ids[e * N_TOK + gr] : 0);
        aptr[j] = xb + (size_t)tok * H_DIM + gch;
    }
    const ushort* bptr[4];
#pragma unroll
    for (int j = 0; j < 4; j++) {
        int r = wv * 32 + j * 8 + rsub;  // 0..127
        const ushort* W = (r < 64) ? (W1 + (size_t)(i0 + r) * H_DIM)
                                   : (W3 + (size_t)(i0 + r - 64) * H_DIM);
        bptr[j] = W + gch;
    }

    int quad = lane >> 4, lr = lane & 15, rx = lr & 7;
    f32x4 acc[2][8] = {};

    const int NK = H_DIM / 64;
    for (int k = 0; k < NK; k++) {
        int off = k * 64;
#pragma unroll
        for (int j = 0; j < 4; j++) async_copy16(aptr[j] + off, &As[wv * 32 + j * 8][0]);
#pragma unroll
        for (int j = 0; j < 4; j++) async_copy16(bptr[j] + off, &Bs[wv * 32 + j * 8][0]);
        __syncthreads();
#pragma unroll
        for (int ks = 0; ks < 2; ks++) {
            int co = ((ks * 4 + quad) ^ rx) * 8;  // swizzled read chunk
            bf16x8 a0 = *(const bf16x8*)&As[wv * 32 + lr][co];
            bf16x8 a1 = *(const bf16x8*)&As[wv * 32 + 16 + lr][co];
#pragma unroll
            for (int ni = 0; ni < 8; ni++) {
                bf16x8 bf = *(const bf16x8*)&Bs[ni * 16 + lr][co];
                acc[0][ni] = __builtin_amdgcn_mfma_f32_16x16x32_bf16(a0, bf, acc[0][ni], 0, 0, 0);
                acc[1][ni] = __builtin_amdgcn_mfma_f32_16x16x32_bf16(a1, bf, acc[1][ni], 0, 0, 0);
            }
        }
        __syncthreads();
    }

    // epilogue: g = acc[.][0..3], u = acc[.][4..7] (same lane) -> silu(g)*u*tw
#pragma unroll
    for (int mi = 0; mi < 2; mi++) {
#pragma unroll
        for (int ni = 0; ni < 4; ni++) {
            f32x4 g = acc[mi][ni];
            f32x4 u = acc[mi][ni + 4];
#pragma unroll
            for (int rg = 0; rg < 4; rg++) {
                int ml = wv * 32 + mi * 16 + quad * 4 + rg;
                int row = m0 + ml;
                if (row < Me) {
                    float gg = g[rg], uu = u[rg];
                    float act = (gg / (1.f + expf(-gg))) * uu * tws[ml];
                    hact[(size_t)(base + row) * I_DIM + i0 + ni * 16 + lr] = f2bf(act);
                }
            }
        }
    }
}

// ---------------- stage B: down proj + scatter-add ----------------
// M=128 slots, N=128 of H, BK=64 over I=768; same single-buffer structure.
__launch_bounds__(256, 4)
__global__ void k_down(const ushort* __restrict__ hact, const ushort* __restrict__ wb2,
                       const ushort* __restrict__ wsb2, const int* __restrict__ counts,
                       const int* __restrict__ offsets, const int* __restrict__ tiles,
                       const int* __restrict__ tok_ids, float* __restrict__ out) {
    int desc = tiles[blockIdx.x];
    if (desc < 0) return;
    int e = desc & 31;
    int m0 = (desc >> 5) * 128;
    int h0 = blockIdx.y * 128;
    int Me = (e == N_EXP) ? N_TOK : counts[e];
    const ushort* W2 = (e == N_EXP) ? wsb2 : wb2 + (size_t)e * H_DIM * I_DIM;
    int base = offsets[e];

    __shared__ ushort As[128][64];
    __shared__ ushort Bs[128][64];
    __shared__ int toks[128];

    int tid = threadIdx.x;
    int wv = tid >> 6, lane = tid & 63;
    int seg = lane & 7, rsub = lane >> 3;
    int gch = (seg ^ rsub) * 8;

    if (tid < 128) {
        int r = m0 + tid;
        toks[tid] = (e == N_EXP) ? r : ((r < Me) ? tok_ids[e * N_TOK + r] : 0);
    }

    const ushort* aptr[4];
#pragma unroll
    for (int j = 0; j < 4; j++) {
        int row = wv * 32 + j * 8 + rsub;
        aptr[j] = hact + (size_t)(base + m0 + row) * I_DIM + gch;
    }
    const ushort* bptr[4];
#pragma unroll
    for (int j = 0; j < 4; j++) {
        int r = wv * 32 + j * 8 + rsub;
        bptr[j] = W2 + (size_t)(h0 + r) * I_DIM + gch;
    }

    int quad = lane >> 4, lr = lane & 15, rx = lr & 7;
    f32x4 acc[2][8] = {};

    const int NK = I_DIM / 64;
    for (int k = 0; k < NK; k++) {
        int off = k * 64;
#pragma unroll
        for (int j = 0; j < 4; j++) async_copy16(aptr[j] + off, &As[wv * 32 + j * 8][0]);
#pragma unroll
        for (int j = 0; j < 4; j++) async_copy16(bptr[j] + off, &Bs[wv * 32 + j * 8][0]);
        __syncthreads();
#pragma unroll
        for (int ks = 0; ks < 2; ks++) {
            int co = ((ks * 4 + quad) ^ rx) * 8;
            bf16x8 a0 = *(const bf16x8*)&As[wv * 32 + lr][co];
            bf16x8 a1 = *(const bf16x8*)&As[wv * 32 + 16 + lr][co];
#pragma unroll
            for (int ni = 0; ni < 8; ni++) {
                bf16x8 bf = *(const bf16x8*)&Bs[ni * 16 + lr][co];
                acc[0][ni] = __builtin_amdgcn_mfma_f32_16x16x32_bf16(a0, bf, acc[0][ni], 0, 0, 0);
                acc[1][ni] = __builtin_amdgcn_mfma_f32_16x16x32_bf16(a1, bf, acc[1][ni], 0, 0, 0);
            }
        }
        __syncthreads();
    }

#pragma unroll
    for (int mi = 0; mi < 2; mi++) {
#pragma unroll
        for (int ni = 0; ni < 8; ni++) {
#pragma unroll
            for (int rg = 0; rg < 4; rg++) {
                int ml = wv * 32 + mi * 16 + quad * 4 + rg;
                int row = m0 + ml;
                if (row < Me) {
                    int tok = toks[ml];
                    atomicAdd(&out[(size_t)tok * H_DIM + h0 + ni * 16 + lr],
                              acc[mi][ni][rg]);
                }
            }
        }
    }
}

extern "C" void kernel_launch(void* const* d_in, const int* in_sizes, int n_in,
                              void* d_out, int out_size, void* d_ws, size_t ws_size,
                              hipStream_t stream) {
    const float* x   = (const float*)d_in[0];
    const float* gw  = (const float*)d_in[1];
    const float* gb  = (const float*)d_in[2];
    const float* w1  = (const float*)d_in[3];
    const float* w2  = (const float*)d_in[4];
    const float* w3  = (const float*)d_in[5];
    const float* ws1 = (const float*)d_in[6];
    const float* ws2 = (const float*)d_in[7];
    const float* ws3 = (const float*)d_in[8];
    float* out = (float*)d_out;

    char* wsb = (char*)d_ws;
    int* counts   = (int*)(wsb + OFF_COUNTS);
    int* offsets  = (int*)(wsb + OFF_OFFSETS);
    int* tiles    = (int*)(wsb + OFF_TILES);
    int* tok_ids  = (int*)(wsb + OFF_TOKIDS);
    float* tok_w  = (float*)(wsb + OFF_TOKW);
    ushort* xb    = (ushort*)(wsb + OFF_XB);
    ushort* hact  = (ushort*)(wsb + OFF_HACT);
    ushort* wb1   = (ushort*)(wsb + OFF_WB1);
    ushort* wb2   = (ushort*)(wsb + OFF_WB2);
    ushort* wb3   = (ushort*)(wsb + OFF_WB3);
    ushort* wsb1  = (ushort*)(wsb + OFF_WSB1);
    ushort* wsb2  = (ushort*)(wsb + OFF_WSB2);
    ushort* wsb3  = (ushort*)(wsb + OFF_WSB3);
    float* gwT    = (float*)(wsb + OFF_GWT);

    hipMemsetAsync(wsb, 0, 128, stream);                       // counts
    hipMemsetAsync(d_out, 0, (size_t)out_size * 4, stream);    // zero outputs

    WcArgs wa;
    wa.src[0] = w1;  wa.dst[0] = wb1;  wa.n4[0] = N_EXP * I_DIM * H_DIM / 4;
    wa.src[1] = w2;  wa.dst[1] = wb2;  wa.n4[1] = N_EXP * H_DIM * I_DIM / 4;
    wa.src[2] = w3;  wa.dst[2] = wb3;  wa.n4[2] = N_EXP * I_DIM * H_DIM / 4;
    wa.src[3] = ws1; wa.dst[3] = wsb1; wa.n4[3] = I_DIM * H_DIM / 4;
    wa.src[4] = ws2; wa.dst[4] = wsb2; wa.n4[4] = H_DIM * I_DIM / 4;
    wa.src[5] = ws3; wa.dst[5] = wsb3; wa.n4[5] = I_DIM * H_DIM / 4;
    wa.src[6] = x;   wa.dst[6] = xb;   wa.n4[6] = N_TOK * H_DIM / 4;
    k_wconv<<<dim3(3072, 7), 256, 0, stream>>>(wa);

    k_gwt<<<N_EXP * H_DIM / 256, 256, 0, stream>>>(gw, gwT);
    k_route<<<N_TOK / 4, 256, 0, stream>>>(x, gwT, gb, counts, tok_ids, tok_w);
    k_scan<<<1, 1, 0, stream>>>(counts, offsets, tiles);
    {
        dim3 grid(MAX_TILES, I_DIM / 64);
        k_gateup<<<grid, 256, 0, stream>>>(xb, wb1, wb3, wsb1, wsb3, counts, offsets,
                                           tiles, tok_ids, tok_w, hact);
    }
    {
        dim3 grid(MAX_TILES, H_DIM / 128);
        k_down<<<grid, 256, 0, stream>>>(hact, wb2, wsb2, counts, offsets, tiles,
                                         tok_ids, out);
    }
}